// Round 10
// baseline (288.263 us; speedup 1.0000x reference)
//
#include <hip/hip_runtime.h>
#include <hip/hip_bf16.h>

#define T_TOK 16384
#define DMODEL 768
#define DFF 3072
#define NEXP 4
#define BK 64
#define MBLK_MAX (T_TOK / 128 + NEXP)   // 132

typedef __attribute__((ext_vector_type(8))) short bf16x8;
typedef __attribute__((ext_vector_type(4))) float f32x4;

__device__ __forceinline__ void gl_lds16(const void* g, void* l) {
  __builtin_amdgcn_global_load_lds(
      (const __attribute__((address_space(1))) unsigned int*)g,
      (__attribute__((address_space(3))) unsigned int*)l, 16, 0, 0);
}

__device__ __forceinline__ short f2bf(float f) {
  union { float f; unsigned u; } v; v.f = f;
  unsigned r = v.u + 0x7fff + ((v.u >> 16) & 1);   // RTNE
  return (short)(r >> 16);
}

__device__ __forceinline__ float gelu_f(float x) {
  const float c = 0.7978845608028654f;              // tanh-approx gelu (JAX default)
  float z = c * (x + 0.044715f * x * x * x);
  z = fminf(fmaxf(z, -15.f), 15.f);
  float e = __expf(-2.f * z);
  return 0.5f * x * (1.f + (1.f - e) / (1.f + e));
}

// tiled layouts (all 64x64-bf16 tiles, 4096 shorts each; swizzle: 16B-chunk u of
// row r stored at u^(r&7)):
//   xg : [mblk][DMODEL/64][128][64]   (two 64-row tiles stacked -> 8192-short blob)
//   w1t: [E][DMODEL/64][DFF/64][64][64]
//   w2t: [E][DFF/64][DMODEL/64][64][64]
//   h  : [mblk][FFC/64][128][64]

// aligned expert offsets (multiples of 128 so row parity == global parity)
__device__ __forceinline__ int expert_aoff(const int* counts, int e) {
  int off = 0;
  for (int i = 0; i < e; ++i) off += (counts[i] + 127) & ~127;
  return off;
}

// ---------------- route: fp32 logits, softmax, argmax — NO atomics ----------
__global__ void route_kernel(const float* __restrict__ x, const float* __restrict__ Wg,
                             const float* __restrict__ bg, int* __restrict__ route,
                             float* __restrict__ gate) {
  int t = blockIdx.x * 4 + (threadIdx.x >> 6);
  int l = threadIdx.x & 63;
  const float* xr = x + (size_t)t * DMODEL;
  float s0 = 0.f, s1 = 0.f, s2 = 0.f, s3 = 0.f;
#pragma unroll
  for (int i = 0; i < DMODEL / 64; ++i) {
    int d = l + i * 64;
    float xv = xr[d];
    float4 w = *((const float4*)Wg + d);
    s0 += xv * w.x; s1 += xv * w.y; s2 += xv * w.z; s3 += xv * w.w;
  }
#pragma unroll
  for (int off = 32; off; off >>= 1) {
    s0 += __shfl_xor(s0, off);
    s1 += __shfl_xor(s1, off);
    s2 += __shfl_xor(s2, off);
    s3 += __shfl_xor(s3, off);
  }
  if (l == 0) {
    float lg[4] = { s0 + bg[0], s1 + bg[1], s2 + bg[2], s3 + bg[3] };
    int best = 0; float m = lg[0];
#pragma unroll
    for (int e = 1; e < 4; ++e) if (lg[e] > m) { m = lg[e]; best = e; }
    float s = 0.f;
#pragma unroll
    for (int e = 0; e < 4; ++e) s += __expf(lg[e] - m);
    route[t] = best;
    gate[t] = 1.0f / s;
  }
}

// ---- bucket: ballot histogram + LDS prefix, 4 atomics per block -------------
__global__ void bucket_kernel(const int* __restrict__ route, int* __restrict__ counts,
                              int* __restrict__ perm) {
  __shared__ int wcnt[4][NEXP];
  __shared__ int wpre[4][NEXP];
  __shared__ int base[NEXP];
  int tid = threadIdx.x;
  int t = blockIdx.x * 256 + tid;
  int w = tid >> 6, l = tid & 63;
  int r = route[t];
  int lanepre = 0;
  unsigned long long lower = (l == 0) ? 0ull : (~0ull >> (64 - l));
#pragma unroll
  for (int e = 0; e < NEXP; ++e) {
    unsigned long long m = __ballot(r == e);
    if (l == 0) wcnt[w][e] = (int)__popcll(m);
    if (r == e) lanepre = (int)__popcll(m & lower);
  }
  __syncthreads();
  if (tid < NEXP) {
    int s = 0;
#pragma unroll
    for (int ww = 0; ww < 4; ++ww) { wpre[ww][tid] = s; s += wcnt[ww][tid]; }
    base[tid] = atomicAdd(&counts[tid], s);
  }
  __syncthreads();
  int pos = base[r] + wpre[w][r] + lanepre;
  perm[r * T_TOK + pos] = t;
}

// --------- gather x rows -> expert-contiguous TILED bf16, swizzled -----------
__global__ void gather_kernel(const float* __restrict__ x, const int* __restrict__ counts,
                              const int* __restrict__ perm, const float* __restrict__ gate,
                              short* __restrict__ xg, int* __restrict__ tokg,
                              float* __restrict__ gateg) {
  int e = blockIdx.y;
  int cnt = counts[e];
  int pos = blockIdx.x * 8 + (threadIdx.x >> 5);
  if (pos >= cnt) return;
  int off = expert_aoff(counts, e);
  int t = perm[e * T_TOK + pos];
  int g = off + pos;
  int l = threadIdx.x & 31;
  const float* src = x + (size_t)t * DMODEL;
  size_t rbase = ((size_t)(g >> 7) * (DMODEL >> 6)) * 8192 + (g & 127) * 64;
  int sw = g & 7;
#pragma unroll
  for (int i = 0; i < 3; ++i) {
    int c = l + 32 * i;                              // 16B chunk index, 0..95
    float4 a = *((const float4*)src + c * 2);
    float4 b = *((const float4*)src + c * 2 + 1);
    bf16x8 v;
    v[0] = f2bf(a.x); v[1] = f2bf(a.y); v[2] = f2bf(a.z); v[3] = f2bf(a.w);
    v[4] = f2bf(b.x); v[5] = f2bf(b.y); v[6] = f2bf(b.z); v[7] = f2bf(b.w);
    int kt = c >> 3, u = c & 7;
    *(bf16x8*)(xg + rbase + (size_t)kt * 8192 + ((u ^ sw) << 3)) = v;
  }
  if (l == 0) { tokg[g] = t; gateg[g] = gate[t]; }
}

// --- transpose tiled: [K][N] fp32 -> [E][K/64][N/64][64][64] bf16 swizzled ---
__global__ void transpose_tiled_kernel(const float* __restrict__ src, short* __restrict__ dst,
                                       int K, int N) {
  __shared__ float lds[64 * 65];
  int e = blockIdx.z;
  int k0 = blockIdx.x * 64, n0 = blockIdx.y * 64;
  const float* s = src + (size_t)e * K * N;
#pragma unroll
  for (int i = 0; i < 16; ++i) {
    int idx = threadIdx.x + i * 256;
    int kk = idx >> 6, nn = idx & 63;
    lds[kk * 65 + nn] = s[(size_t)(k0 + kk) * N + n0 + nn];
  }
  __syncthreads();
  size_t tile = ((size_t)e * (K >> 6) + (k0 >> 6)) * (N >> 6) + (n0 >> 6);
  short* d = dst + tile * 4096;
#pragma unroll
  for (int i = 0; i < 2; ++i) {
    int cid = threadIdx.x + i * 256;
    int nn = cid >> 3, uu = cid & 7;                // row nn (N-dir), chunk uu (K-dir)
    int n = n0 + nn;
    bf16x8 v;
#pragma unroll
    for (int j = 0; j < 8; ++j) v[j] = f2bf(lds[(uu * 8 + j) * 65 + nn]);
    int cs = uu ^ (n & 7);
    *(bf16x8*)(d + nn * 64 + cs * 8) = v;
  }
}

// XCD-bijective chunked decode (m204)
__device__ __forceinline__ int xcd_chunk(int orig, int nwg) {
  int q = nwg >> 3, r = nwg & 7, xcd = orig & 7;
  return (xcd < r ? xcd * (q + 1) : r * (q + 1) + (xcd - r) * q) + (orig >> 3);
}

// expert decode from linear M-block index (tile height = 128)
__device__ __forceinline__ bool decode_expert(const int* counts, int gm,
                                              int& e, int& off, int& cnt, int& m0) {
  int c0 = counts[0], c1 = counts[1], c2 = counts[2], c3 = counts[3];
  int mb0 = (c0 + 127) >> 7, mb1 = (c1 + 127) >> 7, mb2 = (c2 + 127) >> 7, mb3 = (c3 + 127) >> 7;
  int o1 = (c0 + 127) & ~127, o2 = o1 + ((c1 + 127) & ~127), o3 = o2 + ((c2 + 127) & ~127);
  if (gm < mb0)                        { e = 0; off = 0;  cnt = c0; m0 = gm << 7; return true; }
  if (gm < mb0 + mb1)                  { e = 1; off = o1; cnt = c1; m0 = (gm - mb0) << 7; return true; }
  if (gm < mb0 + mb1 + mb2)            { e = 2; off = o2; cnt = c2; m0 = (gm - mb0 - mb1) << 7; return true; }
  if (gm < mb0 + mb1 + mb2 + mb3)      { e = 3; off = o3; cnt = c3; m0 = (gm - mb0 - mb1 - mb2) << 7; return true; }
  return false;
}

// --- GEMM1: 128M x 256N, 8 waves, BK=64, 2-barrier; TILED A/B; tiled h out ---
__global__ __launch_bounds__(512, 2)
void gemm1_kernel(const short* __restrict__ xg, const short* __restrict__ w1t,
                  const float* __restrict__ b1, const int* __restrict__ counts,
                  short* __restrict__ h, int FFC, int chunk, int MBG) {
  __shared__ __align__(16) short smem[32768];           // 64 KB; staging uses 48
  short* sA = smem;                                     // 16 KB  (128 x 64)
  short* sB = smem + 8192;                              // 32 KB  (256 x 64)
  int L = xcd_chunk(blockIdx.x, gridDim.x);
  int np = L / MBG, gm = L - np * MBG;                  // M fastest within N-panel
  int e, off, cnt, m0;
  if (!decode_expert(counts, gm, e, off, cnt, m0)) return;
  (void)cnt;
  int n0c = np * 256;
  int n0g = chunk * FFC + n0c;

  int mblk = (off + m0) >> 7;
  const char* Atile = (const char*)(xg + (size_t)mblk * (DMODEL >> 6) * 8192);
  const int NB = DFF >> 6;                              // 48
  const char* Btile = (const char*)(w1t + (((size_t)e * (DMODEL >> 6)) * NB + (n0g >> 6)) * 4096);

  int tid = threadIdx.x, wid = tid >> 6, lane = tid & 63;
  int wm = wid >> 2, wn = wid & 3;
  int l15 = lane & 15, u4 = lane >> 4;

  f32x4 acc[4][4];
#pragma unroll
  for (int i = 0; i < 4; ++i)
#pragma unroll
    for (int j = 0; j < 4; ++j) acc[i][j] = (f32x4){0.f, 0.f, 0.f, 0.f};

  for (int kt = 0; kt < DMODEL / BK; ++kt) {
    const char* at = Atile + (size_t)kt * 16384;        // contiguous 16 KB
    const char* bt = Btile + (size_t)kt * (NB * 8192);  // contiguous 32 KB (4 tiles)
#pragma unroll
    for (int p = 0; p < 2; ++p) {                       // A: 1024 chunks
      int cc = tid + p * 512;
      gl_lds16(at + cc * 16, (char*)sA + (wid * 64 + p * 512) * 16);
    }
#pragma unroll
    for (int p = 0; p < 4; ++p) {                       // B: 2048 chunks
      int cc = tid + p * 512;
      gl_lds16(bt + cc * 16, (char*)sB + (wid * 64 + p * 512) * 16);
    }
    __syncthreads();
#pragma unroll
    for (int ks = 0; ks < 2; ++ks) {
      int u = ks * 4 + u4;
      int slot8 = (u ^ (l15 & 7)) << 3;
      bf16x8 af[4], bfr[4];
#pragma unroll
      for (int mi = 0; mi < 4; ++mi)
        af[mi] = *(const bf16x8*)&sA[(wm * 64 + mi * 16 + l15) * 64 + slot8];
#pragma unroll
      for (int ni = 0; ni < 4; ++ni)
        bfr[ni] = *(const bf16x8*)&sB[(wn * 64 + ni * 16 + l15) * 64 + slot8];
#pragma unroll
      for (int mi = 0; mi < 4; ++mi)
#pragma unroll
        for (int ni = 0; ni < 4; ++ni)
          acc[mi][ni] = __builtin_amdgcn_mfma_f32_16x16x32_bf16(af[mi], bfr[ni], acc[mi][ni], 0, 0, 0);
    }
    __syncthreads();
  }

  // ---- epilogue: gelu+bias -> 64KB bounce in TILED h layout -> linear copy --
  float bbs[4];
#pragma unroll
  for (int ni = 0; ni < 4; ++ni) bbs[ni] = b1[e * DFF + n0g + wn * 64 + ni * 16 + l15];
#pragma unroll
  for (int mi = 0; mi < 4; ++mi)
#pragma unroll
    for (int ni = 0; ni < 4; ++ni) {
      f32x4 v = acc[mi][ni];
      int col = wn * 64 + ni * 16 + l15;                // 0..255
      int tl = col >> 6, wc = col & 63;
      int u = wc >> 3, o7 = wc & 7;
#pragma unroll
      for (int qq = 0; qq < 4; ++qq) {
        int rl = wm * 64 + mi * 16 + u4 * 4 + qq;       // 0..127; parity == global row&7
        int cs = u ^ (rl & 7);
        smem[tl * 8192 + rl * 64 + cs * 8 + o7] = f2bf(gelu_f(v[qq] + bbs[ni]));
      }
    }
  __syncthreads();
  size_t tb = ((size_t)mblk * (FFC >> 6) + (n0c >> 6)) * 8192;   // shorts
#pragma unroll
  for (int it = 0; it < 8; ++it) {
    int cc = tid + it * 512;                            // 4096 16B chunks = 64 KB
    *(bf16x8*)(h + tb + cc * 8) = *(const bf16x8*)(smem + cc * 8);
  }
}

// ------ GEMM2: 128M x 256N, 8 waves, BK=64, 2-barrier; TILED A/B streams -----
__global__ __launch_bounds__(512, 4)
void gemm2_kernel(const short* __restrict__ h, const short* __restrict__ w2t,
                  const float* __restrict__ b2, const int* __restrict__ counts,
                  const int* __restrict__ tokg, const float* __restrict__ gateg,
                  float* __restrict__ out, int FFC, int chunk, int nchunks, int MBG) {
  __shared__ __align__(16) short sA[128 * 64];          // 16 KB
  __shared__ __align__(16) short sB[256 * 64];          // 32 KB
  int L = xcd_chunk(blockIdx.x, gridDim.x);
  int np = L / MBG, gm = L - np * MBG;                  // M fastest within N-panel
  int e, off, cnt, m0;
  if (!decode_expert(counts, gm, e, off, cnt, m0)) return;
  int n0 = np * 256;

  int mblk = (off + m0) >> 7;
  const char* Atile = (const char*)(h + (size_t)mblk * (FFC >> 6) * 8192);
  const int N64 = DMODEL >> 6;                          // 12
  const char* Btile = (const char*)(w2t + (((size_t)e * (DFF >> 6)) * N64 + (np << 2)) * 4096);
  const int ktg0 = chunk * (FFC >> 6);

  int tid = threadIdx.x, wid = tid >> 6, lane = tid & 63;
  int wm = wid >> 2, wn = wid & 3;
  int l15 = lane & 15, u4 = lane >> 4;

  f32x4 acc[4][4];
#pragma unroll
  for (int i = 0; i < 4; ++i)
#pragma unroll
    for (int j = 0; j < 4; ++j) acc[i][j] = (f32x4){0.f, 0.f, 0.f, 0.f};

  for (int kt = 0; kt < FFC / BK; ++kt) {
    const char* at = Atile + (size_t)kt * 16384;        // contiguous 16 KB
    const char* bt = Btile + (size_t)(ktg0 + kt) * (N64 * 8192);  // contiguous 32 KB
#pragma unroll
    for (int p = 0; p < 2; ++p) {                       // A: 1024 chunks
      int cc = tid + p * 512;
      gl_lds16(at + cc * 16, (char*)sA + (wid * 64 + p * 512) * 16);
    }
#pragma unroll
    for (int p = 0; p < 4; ++p) {                       // B: 2048 chunks
      int cc = tid + p * 512;
      gl_lds16(bt + cc * 16, (char*)sB + (wid * 64 + p * 512) * 16);
    }
    __syncthreads();
#pragma unroll
    for (int ks = 0; ks < 2; ++ks) {
      int u = ks * 4 + u4;
      int slot8 = (u ^ (l15 & 7)) << 3;
      bf16x8 af[4], bfr[4];
#pragma unroll
      for (int mi = 0; mi < 4; ++mi)
        af[mi] = *(const bf16x8*)&sA[(wm * 64 + mi * 16 + l15) * 64 + slot8];
#pragma unroll
      for (int ni = 0; ni < 4; ++ni)
        bfr[ni] = *(const bf16x8*)&sB[(wn * 64 + ni * 16 + l15) * 64 + slot8];
#pragma unroll
      for (int mi = 0; mi < 4; ++mi)
#pragma unroll
        for (int ni = 0; ni < 4; ++ni)
          acc[mi][ni] = __builtin_amdgcn_mfma_f32_16x16x32_bf16(af[mi], bfr[ni], acc[mi][ni], 0, 0, 0);
    }
    __syncthreads();
  }

#pragma unroll
  for (int ni = 0; ni < 4; ++ni) {
    int colg = n0 + wn * 64 + ni * 16 + l15;
    float bb = b2[e * DMODEL + colg];
#pragma unroll
    for (int mi = 0; mi < 4; ++mi) {
      f32x4 v = acc[mi][ni];
#pragma unroll
      for (int qq = 0; qq < 4; ++qq) {
        int ml = m0 + wm * 64 + mi * 16 + u4 * 4 + qq;
        if (ml < cnt) {
          int g = off + ml;
          float* op = out + (size_t)tokg[g] * DMODEL + colg;
          float pv = v[qq];
          if (chunk == 0 && nchunks > 1) {
            *op = pv;
          } else if (chunk < nchunks - 1) {
            *op += pv;
          } else {
            float prev = (nchunks > 1) ? *op : 0.f;
            *op = (prev + pv + bb) * gateg[g];
          }
        }
      }
    }
  }
}

extern "C" void kernel_launch(void* const* d_in, const int* in_sizes, int n_in,
                              void* d_out, int out_size, void* d_ws, size_t ws_size,
                              hipStream_t stream) {
  (void)in_sizes; (void)n_in; (void)out_size;
  const float* x  = (const float*)d_in[0];
  const float* Wg = (const float*)d_in[1];
  const float* bg = (const float*)d_in[2];
  const float* W1 = (const float*)d_in[3];
  const float* b1 = (const float*)d_in[4];
  const float* W2 = (const float*)d_in[5];
  const float* b2 = (const float*)d_in[6];
  float* out = (float*)d_out;
  char* ws = (char*)d_ws;

  size_t cur = 0;
  auto take = [&](size_t bytes) -> size_t {
    cur = (cur + 255) & ~(size_t)255;
    size_t r = cur; cur += bytes; return r;
  };
  size_t o_counts = take(64);
  size_t o_perm  = take((size_t)NEXP * T_TOK * 4);
  size_t o_route = take((size_t)T_TOK * 4);
  size_t o_gate  = take((size_t)T_TOK * 4);
  size_t o_tokg  = take((size_t)(T_TOK + 512) * 4);
  size_t o_gateg = take((size_t)(T_TOK + 512) * 4);
  size_t o_w1t   = take((size_t)NEXP * (DMODEL / 64) * (DFF / 64) * 4096 * 2);
  size_t o_w2t   = take((size_t)NEXP * (DFF / 64) * (DMODEL / 64) * 4096 * 2);
  size_t o_xg    = take((size_t)MBLK_MAX * (DMODEL / 64) * 8192 * 2);
  cur = (cur + 255) & ~(size_t)255;
  size_t o_h = cur;

  int FFC = 256;
  const int cands[4] = {3072, 1536, 768, 256};
  for (int i = 0; i < 4; ++i) {
    size_t hbytes = (size_t)MBLK_MAX * (cands[i] >> 6) * 16384;  // tiled h
    if (o_h + hbytes <= ws_size) { FFC = cands[i]; break; }
  }

  int*   counts = (int*)(ws + o_counts);
  int*   perm   = (int*)(ws + o_perm);
  int*   routeb = (int*)(ws + o_route);
  float* gate   = (float*)(ws + o_gate);
  int*   tokg   = (int*)(ws + o_tokg);
  float* gateg  = (float*)(ws + o_gateg);
  short* w1t    = (short*)(ws + o_w1t);
  short* w2t    = (short*)(ws + o_w2t);
  short* xg     = (short*)(ws + o_xg);
  short* hbuf   = (short*)(ws + o_h);

  hipMemsetAsync(counts, 0, 64, stream);
  route_kernel<<<T_TOK / 4, 256, 0, stream>>>(x, Wg, bg, routeb, gate);
  bucket_kernel<<<T_TOK / 256, 256, 0, stream>>>(routeb, counts, perm);
  transpose_tiled_kernel<<<dim3(DMODEL / 64, DFF / 64, NEXP), 256, 0, stream>>>(W1, w1t, DMODEL, DFF);
  transpose_tiled_kernel<<<dim3(DFF / 64, DMODEL / 64, NEXP), 256, 0, stream>>>(W2, w2t, DFF, DMODEL);
  gather_kernel<<<dim3(T_TOK / 8, NEXP), 256, 0, stream>>>(x, counts, perm, gate, xg, tokg, gateg);

  int NC = DFF / FFC;
  int MBG = T_TOK / 128 + (NEXP - 1);                  // 131 max M-blocks (128-tiles)
  int NB2 = DMODEL / 256;                              // 3
  for (int c = 0; c < NC; ++c) {
    int NB1 = FFC / 256;
    gemm1_kernel<<<NB1 * MBG, 512, 0, stream>>>(xg, w1t, b1, counts, hbuf, FFC, c, MBG);
    gemm2_kernel<<<NB2 * MBG, 512, 0, stream>>>(hbuf, w2t, b2, counts, tokg, gateg, out, FFC, c, NC, MBG);
  }
}

// Round 11
// 276.695 us; speedup vs baseline: 1.0418x; 1.0418x over previous
//
#include <hip/hip_runtime.h>
#include <hip/hip_bf16.h>

#define T_TOK 16384
#define DMODEL 768
#define DFF 3072
#define NEXP 4
#define BK 64
#define MBLK_MAX (T_TOK / 128 + NEXP)   // 132

typedef __attribute__((ext_vector_type(8))) short bf16x8;
typedef __attribute__((ext_vector_type(4))) float f32x4;

__device__ __forceinline__ void gl_lds16(const void* g, void* l) {
  __builtin_amdgcn_global_load_lds(
      (const __attribute__((address_space(1))) unsigned int*)g,
      (__attribute__((address_space(3))) unsigned int*)l, 16, 0, 0);
}

__device__ __forceinline__ short f2bf(float f) {
  union { float f; unsigned u; } v; v.f = f;
  unsigned r = v.u + 0x7fff + ((v.u >> 16) & 1);   // RTNE
  return (short)(r >> 16);
}

__device__ __forceinline__ float gelu_f(float x) {
  const float c = 0.7978845608028654f;              // tanh-approx gelu (JAX default)
  float z = c * (x + 0.044715f * x * x * x);
  z = fminf(fmaxf(z, -15.f), 15.f);
  float e = __expf(-2.f * z);
  return 0.5f * x * (1.f + (1.f - e) / (1.f + e));
}

// tiled layouts (64x64-bf16 tiles, 4096 shorts; swizzle: 16B-chunk u of row r
// stored at u^(r&7)):
//   xg : [mblk][DMODEL/64][128][64]
//   w1t: [E][DMODEL/64][DFF/64][64][64]
//   w2t: [E][DFF/64][DMODEL/64][64][64]
//   h  : [mblk][FFC/64][128][64]

__device__ __forceinline__ int expert_aoff(const int* counts, int e) {
  int off = 0;
  for (int i = 0; i < e; ++i) off += (counts[i] + 127) & ~127;
  return off;
}

// ---------------- route: fp32 logits, softmax, argmax — NO atomics ----------
__global__ void route_kernel(const float* __restrict__ x, const float* __restrict__ Wg,
                             const float* __restrict__ bg, int* __restrict__ route,
                             float* __restrict__ gate) {
  int t = blockIdx.x * 4 + (threadIdx.x >> 6);
  int l = threadIdx.x & 63;
  const float* xr = x + (size_t)t * DMODEL;
  float s0 = 0.f, s1 = 0.f, s2 = 0.f, s3 = 0.f;
#pragma unroll
  for (int i = 0; i < DMODEL / 64; ++i) {
    int d = l + i * 64;
    float xv = xr[d];
    float4 w = *((const float4*)Wg + d);
    s0 += xv * w.x; s1 += xv * w.y; s2 += xv * w.z; s3 += xv * w.w;
  }
#pragma unroll
  for (int off = 32; off; off >>= 1) {
    s0 += __shfl_xor(s0, off);
    s1 += __shfl_xor(s1, off);
    s2 += __shfl_xor(s2, off);
    s3 += __shfl_xor(s3, off);
  }
  if (l == 0) {
    float lg[4] = { s0 + bg[0], s1 + bg[1], s2 + bg[2], s3 + bg[3] };
    int best = 0; float m = lg[0];
#pragma unroll
    for (int e = 1; e < 4; ++e) if (lg[e] > m) { m = lg[e]; best = e; }
    float s = 0.f;
#pragma unroll
    for (int e = 0; e < 4; ++e) s += __expf(lg[e] - m);
    route[t] = best;
    gate[t] = 1.0f / s;
  }
}

// ---- bucket: ballot histogram + LDS prefix, 4 atomics per block -------------
__global__ void bucket_kernel(const int* __restrict__ route, int* __restrict__ counts,
                              int* __restrict__ perm) {
  __shared__ int wcnt[4][NEXP];
  __shared__ int wpre[4][NEXP];
  __shared__ int base[NEXP];
  int tid = threadIdx.x;
  int t = blockIdx.x * 256 + tid;
  int w = tid >> 6, l = tid & 63;
  int r = route[t];
  int lanepre = 0;
  unsigned long long lower = (l == 0) ? 0ull : (~0ull >> (64 - l));
#pragma unroll
  for (int e = 0; e < NEXP; ++e) {
    unsigned long long m = __ballot(r == e);
    if (l == 0) wcnt[w][e] = (int)__popcll(m);
    if (r == e) lanepre = (int)__popcll(m & lower);
  }
  __syncthreads();
  if (tid < NEXP) {
    int s = 0;
#pragma unroll
    for (int ww = 0; ww < 4; ++ww) { wpre[ww][tid] = s; s += wcnt[ww][tid]; }
    base[tid] = atomicAdd(&counts[tid], s);
  }
  __syncthreads();
  int pos = base[r] + wpre[w][r] + lanepre;
  perm[r * T_TOK + pos] = t;
}

// --------- gather x rows -> expert-contiguous TILED bf16, swizzled -----------
__global__ void gather_kernel(const float* __restrict__ x, const int* __restrict__ counts,
                              const int* __restrict__ perm, const float* __restrict__ gate,
                              short* __restrict__ xg, int* __restrict__ tokg,
                              float* __restrict__ gateg) {
  int e = blockIdx.y;
  int cnt = counts[e];
  int pos = blockIdx.x * 8 + (threadIdx.x >> 5);
  if (pos >= cnt) return;
  int off = expert_aoff(counts, e);
  int t = perm[e * T_TOK + pos];
  int g = off + pos;
  int l = threadIdx.x & 31;
  const float* src = x + (size_t)t * DMODEL;
  size_t rbase = ((size_t)(g >> 7) * (DMODEL >> 6)) * 8192 + (g & 127) * 64;
  int sw = g & 7;
#pragma unroll
  for (int i = 0; i < 3; ++i) {
    int c = l + 32 * i;                              // 16B chunk index, 0..95
    float4 a = *((const float4*)src + c * 2);
    float4 b = *((const float4*)src + c * 2 + 1);
    bf16x8 v;
    v[0] = f2bf(a.x); v[1] = f2bf(a.y); v[2] = f2bf(a.z); v[3] = f2bf(a.w);
    v[4] = f2bf(b.x); v[5] = f2bf(b.y); v[6] = f2bf(b.z); v[7] = f2bf(b.w);
    int kt = c >> 3, u = c & 7;
    *(bf16x8*)(xg + rbase + (size_t)kt * 8192 + ((u ^ sw) << 3)) = v;
  }
  if (l == 0) { tokg[g] = t; gateg[g] = gate[t]; }
}

// --- transpose tiled: [K][N] fp32 -> [E][K/64][N/64][64][64] bf16 swizzled ---
__global__ void transpose_tiled_kernel(const float* __restrict__ src, short* __restrict__ dst,
                                       int K, int N) {
  __shared__ float lds[64 * 65];
  int e = blockIdx.z;
  int k0 = blockIdx.x * 64, n0 = blockIdx.y * 64;
  const float* s = src + (size_t)e * K * N;
#pragma unroll
  for (int i = 0; i < 16; ++i) {
    int idx = threadIdx.x + i * 256;
    int kk = idx >> 6, nn = idx & 63;
    lds[kk * 65 + nn] = s[(size_t)(k0 + kk) * N + n0 + nn];
  }
  __syncthreads();
  size_t tile = ((size_t)e * (K >> 6) + (k0 >> 6)) * (N >> 6) + (n0 >> 6);
  short* d = dst + tile * 4096;
#pragma unroll
  for (int i = 0; i < 2; ++i) {
    int cid = threadIdx.x + i * 256;
    int nn = cid >> 3, uu = cid & 7;                // row nn (N-dir), chunk uu (K-dir)
    int n = n0 + nn;
    bf16x8 v;
#pragma unroll
    for (int j = 0; j < 8; ++j) v[j] = f2bf(lds[(uu * 8 + j) * 65 + nn]);
    int cs = uu ^ (n & 7);
    *(bf16x8*)(d + nn * 64 + cs * 8) = v;
  }
}

// XCD-bijective chunked decode (m204)
__device__ __forceinline__ int xcd_chunk(int orig, int nwg) {
  int q = nwg >> 3, r = nwg & 7, xcd = orig & 7;
  return (xcd < r ? xcd * (q + 1) : r * (q + 1) + (xcd - r) * q) + (orig >> 3);
}

// expert decode from linear M-block index (tile height = 128)
__device__ __forceinline__ bool decode_expert(const int* counts, int gm,
                                              int& e, int& off, int& cnt, int& m0) {
  int c0 = counts[0], c1 = counts[1], c2 = counts[2], c3 = counts[3];
  int mb0 = (c0 + 127) >> 7, mb1 = (c1 + 127) >> 7, mb2 = (c2 + 127) >> 7, mb3 = (c3 + 127) >> 7;
  int o1 = (c0 + 127) & ~127, o2 = o1 + ((c1 + 127) & ~127), o3 = o2 + ((c2 + 127) & ~127);
  if (gm < mb0)                        { e = 0; off = 0;  cnt = c0; m0 = gm << 7; return true; }
  if (gm < mb0 + mb1)                  { e = 1; off = o1; cnt = c1; m0 = (gm - mb0) << 7; return true; }
  if (gm < mb0 + mb1 + mb2)            { e = 2; off = o2; cnt = c2; m0 = (gm - mb0 - mb1) << 7; return true; }
  if (gm < mb0 + mb1 + mb2 + mb3)      { e = 3; off = o3; cnt = c3; m0 = (gm - mb0 - mb1 - mb2) << 7; return true; }
  return false;
}

// --- GEMM1: 128x128, 4 waves, BK=64, 2-barrier; TILED A/B; supergroup-16 -----
__global__ __launch_bounds__(256, 4)
void gemm1_kernel(const short* __restrict__ xg, const short* __restrict__ w1t,
                  const float* __restrict__ b1, const int* __restrict__ counts,
                  short* __restrict__ h, int FFC, int chunk, int NPAN) {
  __shared__ __align__(16) short smem[16384];           // 32 KB: sA|sB, reused as bounce
  short* sA = smem;                                     // 16 KB (128 x 64)
  short* sB = smem + 8192;                              // 16 KB (2 x 64 x 64 tiles)
  int L = xcd_chunk(blockIdx.x, gridDim.x);
  int sg = L / (16 * NPAN);
  int r  = L - sg * 16 * NPAN;
  int np = r >> 4, ml = r & 15;                         // panels outer, M inner-16
  int gm = sg * 16 + ml;
  int e, off, cnt, m0;
  if (!decode_expert(counts, gm, e, off, cnt, m0)) return;
  (void)cnt;
  int n0c = np * 128;
  int n0g = chunk * FFC + n0c;

  int mblk = (off + m0) >> 7;
  const char* Atile = (const char*)(xg + (size_t)mblk * (DMODEL >> 6) * 8192);
  const int NB = DFF >> 6;                              // 48
  const char* Btile = (const char*)(w1t + (((size_t)e * (DMODEL >> 6)) * NB + (n0g >> 6)) * 4096);

  int tid = threadIdx.x, wid = tid >> 6, lane = tid & 63;
  int wm = wid >> 1, wn = wid & 1;
  int l15 = lane & 15, u4 = lane >> 4;

  f32x4 acc[4][4];
#pragma unroll
  for (int i = 0; i < 4; ++i)
#pragma unroll
    for (int j = 0; j < 4; ++j) acc[i][j] = (f32x4){0.f, 0.f, 0.f, 0.f};

  for (int kt = 0; kt < DMODEL / BK; ++kt) {
    const char* at = Atile + (size_t)kt * 16384;        // contiguous 16 KB
    const char* bt = Btile + (size_t)kt * (NB * 8192);  // contiguous 16 KB (2 tiles)
#pragma unroll
    for (int p = 0; p < 4; ++p) {
      int cc = tid + p * 256;                           // 1024 chunks each
      gl_lds16(at + cc * 16, (char*)sA + (wid * 64 + p * 256) * 16);
      gl_lds16(bt + cc * 16, (char*)sB + (wid * 64 + p * 256) * 16);
    }
    __syncthreads();
#pragma unroll
    for (int ks = 0; ks < 2; ++ks) {
      int u = ks * 4 + u4;
      int slot8 = (u ^ (l15 & 7)) << 3;
      bf16x8 af[4], bfr[4];
#pragma unroll
      for (int mi = 0; mi < 4; ++mi)
        af[mi] = *(const bf16x8*)&sA[(wm * 64 + mi * 16 + l15) * 64 + slot8];
#pragma unroll
      for (int ni = 0; ni < 4; ++ni) {
        int col = wn * 64 + ni * 16 + l15;              // 0..127
        bfr[ni] = *(const bf16x8*)&sB[(col >> 6) * 4096 + (col & 63) * 64 + slot8];
      }
#pragma unroll
      for (int mi = 0; mi < 4; ++mi)
#pragma unroll
        for (int ni = 0; ni < 4; ++ni)
          acc[mi][ni] = __builtin_amdgcn_mfma_f32_16x16x32_bf16(af[mi], bfr[ni], acc[mi][ni], 0, 0, 0);
    }
    __syncthreads();
  }

  // ---- epilogue: gelu+bias -> 32KB bounce in TILED h layout -> linear copy --
  float bbs[4];
#pragma unroll
  for (int ni = 0; ni < 4; ++ni) bbs[ni] = b1[e * DFF + n0g + wn * 64 + ni * 16 + l15];
#pragma unroll
  for (int mi = 0; mi < 4; ++mi)
#pragma unroll
    for (int ni = 0; ni < 4; ++ni) {
      f32x4 v = acc[mi][ni];
      int col = wn * 64 + ni * 16 + l15;                // 0..127
      int tl = col >> 6, wc = col & 63;
      int u = wc >> 3, o7 = wc & 7;
#pragma unroll
      for (int qq = 0; qq < 4; ++qq) {
        int rl = wm * 64 + mi * 16 + u4 * 4 + qq;       // 0..127; parity == global row&7
        int cs = u ^ (rl & 7);
        smem[tl * 8192 + rl * 64 + cs * 8 + o7] = f2bf(gelu_f(v[qq] + bbs[ni]));
      }
    }
  __syncthreads();
  size_t tb = ((size_t)mblk * (FFC >> 6) + (n0c >> 6)) * 8192;   // shorts
#pragma unroll
  for (int it = 0; it < 8; ++it) {
    int cc = tid + it * 256;                            // 2048 16B chunks = 32 KB
    *(bf16x8*)(h + tb + cc * 8) = *(const bf16x8*)(smem + cc * 8);
  }
}

// ------ GEMM2: 128M x 256N, 8 waves, BK=64, 2-barrier; TILED A/B streams -----
__global__ __launch_bounds__(512, 4)
void gemm2_kernel(const short* __restrict__ h, const short* __restrict__ w2t,
                  const float* __restrict__ b2, const int* __restrict__ counts,
                  const int* __restrict__ tokg, const float* __restrict__ gateg,
                  float* __restrict__ out, int FFC, int chunk, int nchunks, int MBG) {
  __shared__ __align__(16) short sA[128 * 64];          // 16 KB
  __shared__ __align__(16) short sB[256 * 64];          // 32 KB
  int L = xcd_chunk(blockIdx.x, gridDim.x);
  int np = L / MBG, gm = L - np * MBG;                  // M fastest within N-panel
  int e, off, cnt, m0;
  if (!decode_expert(counts, gm, e, off, cnt, m0)) return;
  int n0 = np * 256;

  int mblk = (off + m0) >> 7;
  const char* Atile = (const char*)(h + (size_t)mblk * (FFC >> 6) * 8192);
  const int N64 = DMODEL >> 6;                          // 12
  const char* Btile = (const char*)(w2t + (((size_t)e * (DFF >> 6)) * N64 + (np << 2)) * 4096);
  const int ktg0 = chunk * (FFC >> 6);

  int tid = threadIdx.x, wid = tid >> 6, lane = tid & 63;
  int wm = wid >> 2, wn = wid & 3;
  int l15 = lane & 15, u4 = lane >> 4;

  f32x4 acc[4][4];
#pragma unroll
  for (int i = 0; i < 4; ++i)
#pragma unroll
    for (int j = 0; j < 4; ++j) acc[i][j] = (f32x4){0.f, 0.f, 0.f, 0.f};

  for (int kt = 0; kt < FFC / BK; ++kt) {
    const char* at = Atile + (size_t)kt * 16384;        // contiguous 16 KB
    const char* bt = Btile + (size_t)(ktg0 + kt) * (N64 * 8192);  // contiguous 32 KB
#pragma unroll
    for (int p = 0; p < 2; ++p) {                       // A: 1024 chunks
      int cc = tid + p * 512;
      gl_lds16(at + cc * 16, (char*)sA + (wid * 64 + p * 512) * 16);
    }
#pragma unroll
    for (int p = 0; p < 4; ++p) {                       // B: 2048 chunks
      int cc = tid + p * 512;
      gl_lds16(bt + cc * 16, (char*)sB + (wid * 64 + p * 512) * 16);
    }
    __syncthreads();
#pragma unroll
    for (int ks = 0; ks < 2; ++ks) {
      int u = ks * 4 + u4;
      int slot8 = (u ^ (l15 & 7)) << 3;
      bf16x8 af[4], bfr[4];
#pragma unroll
      for (int mi = 0; mi < 4; ++mi)
        af[mi] = *(const bf16x8*)&sA[(wm * 64 + mi * 16 + l15) * 64 + slot8];
#pragma unroll
      for (int ni = 0; ni < 4; ++ni)
        bfr[ni] = *(const bf16x8*)&sB[(wn * 64 + ni * 16 + l15) * 64 + slot8];
#pragma unroll
      for (int mi = 0; mi < 4; ++mi)
#pragma unroll
        for (int ni = 0; ni < 4; ++ni)
          acc[mi][ni] = __builtin_amdgcn_mfma_f32_16x16x32_bf16(af[mi], bfr[ni], acc[mi][ni], 0, 0, 0);
    }
    __syncthreads();
  }

#pragma unroll
  for (int ni = 0; ni < 4; ++ni) {
    int colg = n0 + wn * 64 + ni * 16 + l15;
    float bb = b2[e * DMODEL + colg];
#pragma unroll
    for (int mi = 0; mi < 4; ++mi) {
      f32x4 v = acc[mi][ni];
#pragma unroll
      for (int qq = 0; qq < 4; ++qq) {
        int ml = m0 + wm * 64 + mi * 16 + u4 * 4 + qq;
        if (ml < cnt) {
          int g = off + ml;
          float* op = out + (size_t)tokg[g] * DMODEL + colg;
          float pv = v[qq];
          if (chunk == 0 && nchunks > 1) {
            *op = pv;
          } else if (chunk < nchunks - 1) {
            *op += pv;
          } else {
            float prev = (nchunks > 1) ? *op : 0.f;
            *op = (prev + pv + bb) * gateg[g];
          }
        }
      }
    }
  }
}

extern "C" void kernel_launch(void* const* d_in, const int* in_sizes, int n_in,
                              void* d_out, int out_size, void* d_ws, size_t ws_size,
                              hipStream_t stream) {
  (void)in_sizes; (void)n_in; (void)out_size;
  const float* x  = (const float*)d_in[0];
  const float* Wg = (const float*)d_in[1];
  const float* bg = (const float*)d_in[2];
  const float* W1 = (const float*)d_in[3];
  const float* b1 = (const float*)d_in[4];
  const float* W2 = (const float*)d_in[5];
  const float* b2 = (const float*)d_in[6];
  float* out = (float*)d_out;
  char* ws = (char*)d_ws;

  size_t cur = 0;
  auto take = [&](size_t bytes) -> size_t {
    cur = (cur + 255) & ~(size_t)255;
    size_t r = cur; cur += bytes; return r;
  };
  size_t o_counts = take(64);
  size_t o_perm  = take((size_t)NEXP * T_TOK * 4);
  size_t o_route = take((size_t)T_TOK * 4);
  size_t o_gate  = take((size_t)T_TOK * 4);
  size_t o_tokg  = take((size_t)(T_TOK + 512) * 4);
  size_t o_gateg = take((size_t)(T_TOK + 512) * 4);
  size_t o_w1t   = take((size_t)NEXP * (DMODEL / 64) * (DFF / 64) * 4096 * 2);
  size_t o_w2t   = take((size_t)NEXP * (DFF / 64) * (DMODEL / 64) * 4096 * 2);
  size_t o_xg    = take((size_t)MBLK_MAX * (DMODEL / 64) * 8192 * 2);
  cur = (cur + 255) & ~(size_t)255;
  size_t o_h = cur;

  int FFC = 256;
  const int cands[4] = {3072, 1536, 768, 256};
  for (int i = 0; i < 4; ++i) {
    size_t hbytes = (size_t)MBLK_MAX * (cands[i] >> 6) * 16384;  // tiled h
    if (o_h + hbytes <= ws_size) { FFC = cands[i]; break; }
  }

  int*   counts = (int*)(ws + o_counts);
  int*   perm   = (int*)(ws + o_perm);
  int*   routeb = (int*)(ws + o_route);
  float* gate   = (float*)(ws + o_gate);
  int*   tokg   = (int*)(ws + o_tokg);
  float* gateg  = (float*)(ws + o_gateg);
  short* w1t    = (short*)(ws + o_w1t);
  short* w2t    = (short*)(ws + o_w2t);
  short* xg     = (short*)(ws + o_xg);
  short* hbuf   = (short*)(ws + o_h);

  hipMemsetAsync(counts, 0, 64, stream);
  route_kernel<<<T_TOK / 4, 256, 0, stream>>>(x, Wg, bg, routeb, gate);
  bucket_kernel<<<T_TOK / 256, 256, 0, stream>>>(routeb, counts, perm);
  transpose_tiled_kernel<<<dim3(DMODEL / 64, DFF / 64, NEXP), 256, 0, stream>>>(W1, w1t, DMODEL, DFF);
  transpose_tiled_kernel<<<dim3(DFF / 64, DMODEL / 64, NEXP), 256, 0, stream>>>(W2, w2t, DFF, DMODEL);
  gather_kernel<<<dim3(T_TOK / 8, NEXP), 256, 0, stream>>>(x, counts, perm, gate, xg, tokg, gateg);

  int NC = DFF / FFC;
  int MBG = T_TOK / 128 + (NEXP - 1);                  // 131 max M-blocks (128-tiles)
  int NB2 = DMODEL / 256;                              // 3
  for (int c = 0; c < NC; ++c) {
    int NPAN = FFC / 128;
    int SGC = (MBG + 15) / 16;                         // 9 supergroups
    gemm1_kernel<<<SGC * 16 * NPAN, 256, 0, stream>>>(xg, w1t, b1, counts, hbuf, FFC, c, NPAN);
    gemm2_kernel<<<NB2 * MBG, 512, 0, stream>>>(hbuf, w2t, b2, counts, tokg, gateg, out, FFC, c, NC, MBG);
  }
}

// Round 12
// 267.120 us; speedup vs baseline: 1.0792x; 1.0358x over previous
//
#include <hip/hip_runtime.h>
#include <hip/hip_bf16.h>

#define T_TOK 16384
#define DMODEL 768
#define DFF 3072
#define NEXP 4
#define BK 64
#define MBLK_MAX (T_TOK / 128 + NEXP)   // 132

typedef __attribute__((ext_vector_type(8))) short bf16x8;
typedef __attribute__((ext_vector_type(4))) float f32x4;

__device__ __forceinline__ void gl_lds16(const void* g, void* l) {
  __builtin_amdgcn_global_load_lds(
      (const __attribute__((address_space(1))) unsigned int*)g,
      (__attribute__((address_space(3))) unsigned int*)l, 16, 0, 0);
}

__device__ __forceinline__ short f2bf(float f) {
  union { float f; unsigned u; } v; v.f = f;
  unsigned r = v.u + 0x7fff + ((v.u >> 16) & 1);   // RTNE
  return (short)(r >> 16);
}

__device__ __forceinline__ float gelu_f(float x) {
  // tanh-approx gelu in sigmoid form: 0.5x(1+tanh(z)) == x * sigmoid(2z)
  const float c2 = 1.5957691216057308f;             // 2*sqrt(2/pi)
  float z2 = c2 * (x + 0.044715f * x * x * x);
  z2 = fminf(fmaxf(z2, -30.f), 30.f);
  return x * __frcp_rn(1.f + __expf(-z2));
}

// tiled layouts (64x64-bf16 tiles, 4096 shorts; swizzle: 16B-chunk u of row r
// stored at u^(r&7)):
//   xg : [mblk][DMODEL/64][128][64]
//   w1t: [E][DMODEL/64][DFF/64][64][64]
//   w2t: [E][DFF/64][DMODEL/64][64][64]
//   h  : [mblk][FFC/64][128][64]

__device__ __forceinline__ int expert_aoff(const int* counts, int e) {
  int off = 0;
  for (int i = 0; i < e; ++i) off += (counts[i] + 127) & ~127;
  return off;
}

// ---------------- route: fp32 logits, softmax, argmax — NO atomics ----------
__global__ void route_kernel(const float* __restrict__ x, const float* __restrict__ Wg,
                             const float* __restrict__ bg, int* __restrict__ route,
                             float* __restrict__ gate) {
  int t = blockIdx.x * 4 + (threadIdx.x >> 6);
  int l = threadIdx.x & 63;
  const float* xr = x + (size_t)t * DMODEL;
  float s0 = 0.f, s1 = 0.f, s2 = 0.f, s3 = 0.f;
#pragma unroll
  for (int i = 0; i < DMODEL / 64; ++i) {
    int d = l + i * 64;
    float xv = xr[d];
    float4 w = *((const float4*)Wg + d);
    s0 += xv * w.x; s1 += xv * w.y; s2 += xv * w.z; s3 += xv * w.w;
  }
#pragma unroll
  for (int off = 32; off; off >>= 1) {
    s0 += __shfl_xor(s0, off);
    s1 += __shfl_xor(s1, off);
    s2 += __shfl_xor(s2, off);
    s3 += __shfl_xor(s3, off);
  }
  if (l == 0) {
    float lg[4] = { s0 + bg[0], s1 + bg[1], s2 + bg[2], s3 + bg[3] };
    int best = 0; float m = lg[0];
#pragma unroll
    for (int e = 1; e < 4; ++e) if (lg[e] > m) { m = lg[e]; best = e; }
    float s = 0.f;
#pragma unroll
    for (int e = 0; e < 4; ++e) s += __expf(lg[e] - m);
    route[t] = best;
    gate[t] = 1.0f / s;
  }
}

// ---- bucket: ballot histogram + LDS prefix, 4 atomics per block -------------
__global__ void bucket_kernel(const int* __restrict__ route, int* __restrict__ counts,
                              int* __restrict__ perm) {
  __shared__ int wcnt[4][NEXP];
  __shared__ int wpre[4][NEXP];
  __shared__ int base[NEXP];
  int tid = threadIdx.x;
  int t = blockIdx.x * 256 + tid;
  int w = tid >> 6, l = tid & 63;
  int r = route[t];
  int lanepre = 0;
  unsigned long long lower = (l == 0) ? 0ull : (~0ull >> (64 - l));
#pragma unroll
  for (int e = 0; e < NEXP; ++e) {
    unsigned long long m = __ballot(r == e);
    if (l == 0) wcnt[w][e] = (int)__popcll(m);
    if (r == e) lanepre = (int)__popcll(m & lower);
  }
  __syncthreads();
  if (tid < NEXP) {
    int s = 0;
#pragma unroll
    for (int ww = 0; ww < 4; ++ww) { wpre[ww][tid] = s; s += wcnt[ww][tid]; }
    base[tid] = atomicAdd(&counts[tid], s);
  }
  __syncthreads();
  int pos = base[r] + wpre[w][r] + lanepre;
  perm[r * T_TOK + pos] = t;
}

// --------- gather x rows -> expert-contiguous TILED bf16, swizzled -----------
__global__ void gather_kernel(const float* __restrict__ x, const int* __restrict__ counts,
                              const int* __restrict__ perm, const float* __restrict__ gate,
                              short* __restrict__ xg, int* __restrict__ tokg,
                              float* __restrict__ gateg) {
  int e = blockIdx.y;
  int cnt = counts[e];
  int pos = blockIdx.x * 8 + (threadIdx.x >> 5);
  if (pos >= cnt) return;
  int off = expert_aoff(counts, e);
  int t = perm[e * T_TOK + pos];
  int g = off + pos;
  int l = threadIdx.x & 31;
  const float* src = x + (size_t)t * DMODEL;
  size_t rbase = ((size_t)(g >> 7) * (DMODEL >> 6)) * 8192 + (g & 127) * 64;
  int sw = g & 7;
#pragma unroll
  for (int i = 0; i < 3; ++i) {
    int c = l + 32 * i;                              // 16B chunk index, 0..95
    float4 a = *((const float4*)src + c * 2);
    float4 b = *((const float4*)src + c * 2 + 1);
    bf16x8 v;
    v[0] = f2bf(a.x); v[1] = f2bf(a.y); v[2] = f2bf(a.z); v[3] = f2bf(a.w);
    v[4] = f2bf(b.x); v[5] = f2bf(b.y); v[6] = f2bf(b.z); v[7] = f2bf(b.w);
    int kt = c >> 3, u = c & 7;
    *(bf16x8*)(xg + rbase + (size_t)kt * 8192 + ((u ^ sw) << 3)) = v;
  }
  if (l == 0) { tokg[g] = t; gateg[g] = gate[t]; }
}

// --- transpose tiled: [K][N] fp32 -> [E][K/64][N/64][64][64] bf16 swizzled ---
__global__ void transpose_tiled_kernel(const float* __restrict__ src, short* __restrict__ dst,
                                       int K, int N) {
  __shared__ float lds[64 * 65];
  int e = blockIdx.z;
  int k0 = blockIdx.x * 64, n0 = blockIdx.y * 64;
  const float* s = src + (size_t)e * K * N;
#pragma unroll
  for (int i = 0; i < 16; ++i) {
    int idx = threadIdx.x + i * 256;
    int kk = idx >> 6, nn = idx & 63;
    lds[kk * 65 + nn] = s[(size_t)(k0 + kk) * N + n0 + nn];
  }
  __syncthreads();
  size_t tile = ((size_t)e * (K >> 6) + (k0 >> 6)) * (N >> 6) + (n0 >> 6);
  short* d = dst + tile * 4096;
#pragma unroll
  for (int i = 0; i < 2; ++i) {
    int cid = threadIdx.x + i * 256;
    int nn = cid >> 3, uu = cid & 7;                // row nn (N-dir), chunk uu (K-dir)
    int n = n0 + nn;
    bf16x8 v;
#pragma unroll
    for (int j = 0; j < 8; ++j) v[j] = f2bf(lds[(uu * 8 + j) * 65 + nn]);
    int cs = uu ^ (n & 7);
    *(bf16x8*)(d + nn * 64 + cs * 8) = v;
  }
}

// XCD-bijective chunked decode (m204)
__device__ __forceinline__ int xcd_chunk(int orig, int nwg) {
  int q = nwg >> 3, r = nwg & 7, xcd = orig & 7;
  return (xcd < r ? xcd * (q + 1) : r * (q + 1) + (xcd - r) * q) + (orig >> 3);
}

// expert decode from linear M-block index (tile height = 128)
__device__ __forceinline__ bool decode_expert(const int* counts, int gm,
                                              int& e, int& off, int& cnt, int& m0) {
  int c0 = counts[0], c1 = counts[1], c2 = counts[2], c3 = counts[3];
  int mb0 = (c0 + 127) >> 7, mb1 = (c1 + 127) >> 7, mb2 = (c2 + 127) >> 7, mb3 = (c3 + 127) >> 7;
  int o1 = (c0 + 127) & ~127, o2 = o1 + ((c1 + 127) & ~127), o3 = o2 + ((c2 + 127) & ~127);
  if (gm < mb0)                        { e = 0; off = 0;  cnt = c0; m0 = gm << 7; return true; }
  if (gm < mb0 + mb1)                  { e = 1; off = o1; cnt = c1; m0 = (gm - mb0) << 7; return true; }
  if (gm < mb0 + mb1 + mb2)            { e = 2; off = o2; cnt = c2; m0 = (gm - mb0 - mb1) << 7; return true; }
  if (gm < mb0 + mb1 + mb2 + mb3)      { e = 3; off = o3; cnt = c3; m0 = (gm - mb0 - mb1 - mb2) << 7; return true; }
  return false;
}

// --- GEMM1: 128x128, 4 waves, BK=64, 2-barrier; TILED A/B; supergroup-16 -----
__global__ __launch_bounds__(256, 4)
void gemm1_kernel(const short* __restrict__ xg, const short* __restrict__ w1t,
                  const float* __restrict__ b1, const int* __restrict__ counts,
                  short* __restrict__ h, int FFC, int chunk, int NPAN) {
  __shared__ __align__(16) short smem[16384];           // 32 KB: sA|sB, reused as bounce
  short* sA = smem;                                     // 16 KB (128 x 64)
  short* sB = smem + 8192;                              // 16 KB (2 x 64 x 64 tiles)
  int L = xcd_chunk(blockIdx.x, gridDim.x);
  int sg = L / (16 * NPAN);
  int r  = L - sg * 16 * NPAN;
  int np = r >> 4, ml = r & 15;                         // panels outer, M inner-16
  int gm = sg * 16 + ml;
  int e, off, cnt, m0;
  if (!decode_expert(counts, gm, e, off, cnt, m0)) return;
  (void)cnt;
  int n0c = np * 128;
  int n0g = chunk * FFC + n0c;

  int mblk = (off + m0) >> 7;
  const char* Atile = (const char*)(xg + (size_t)mblk * (DMODEL >> 6) * 8192);
  const int NB = DFF >> 6;                              // 48
  const char* Btile = (const char*)(w1t + (((size_t)e * (DMODEL >> 6)) * NB + (n0g >> 6)) * 4096);

  int tid = threadIdx.x, wid = tid >> 6, lane = tid & 63;
  int wm = wid >> 1, wn = wid & 1;
  int l15 = lane & 15, u4 = lane >> 4;

  f32x4 acc[4][4];
#pragma unroll
  for (int i = 0; i < 4; ++i)
#pragma unroll
    for (int j = 0; j < 4; ++j) acc[i][j] = (f32x4){0.f, 0.f, 0.f, 0.f};

  for (int kt = 0; kt < DMODEL / BK; ++kt) {
    const char* at = Atile + (size_t)kt * 16384;        // contiguous 16 KB
    const char* bt = Btile + (size_t)kt * (NB * 8192);  // contiguous 16 KB (2 tiles)
#pragma unroll
    for (int p = 0; p < 4; ++p) {
      int cc = tid + p * 256;                           // 1024 chunks each
      gl_lds16(at + cc * 16, (char*)sA + (wid * 64 + p * 256) * 16);
      gl_lds16(bt + cc * 16, (char*)sB + (wid * 64 + p * 256) * 16);
    }
    __syncthreads();
#pragma unroll
    for (int ks = 0; ks < 2; ++ks) {
      int u = ks * 4 + u4;
      int slot8 = (u ^ (l15 & 7)) << 3;
      bf16x8 af[4], bfr[4];
#pragma unroll
      for (int mi = 0; mi < 4; ++mi)
        af[mi] = *(const bf16x8*)&sA[(wm * 64 + mi * 16 + l15) * 64 + slot8];
#pragma unroll
      for (int ni = 0; ni < 4; ++ni) {
        int col = wn * 64 + ni * 16 + l15;              // 0..127
        bfr[ni] = *(const bf16x8*)&sB[(col >> 6) * 4096 + (col & 63) * 64 + slot8];
      }
#pragma unroll
      for (int mi = 0; mi < 4; ++mi)
#pragma unroll
        for (int ni = 0; ni < 4; ++ni)
          acc[mi][ni] = __builtin_amdgcn_mfma_f32_16x16x32_bf16(af[mi], bfr[ni], acc[mi][ni], 0, 0, 0);
    }
    __syncthreads();
  }

  // ---- epilogue: gelu+bias -> 32KB bounce in TILED h layout -> linear copy --
  float bbs[4];
#pragma unroll
  for (int ni = 0; ni < 4; ++ni) bbs[ni] = b1[e * DFF + n0g + wn * 64 + ni * 16 + l15];
#pragma unroll
  for (int mi = 0; mi < 4; ++mi)
#pragma unroll
    for (int ni = 0; ni < 4; ++ni) {
      f32x4 v = acc[mi][ni];
      int col = wn * 64 + ni * 16 + l15;                // 0..127
      int tl = col >> 6, wc = col & 63;
      int u = wc >> 3, o7 = wc & 7;
#pragma unroll
      for (int qq = 0; qq < 4; ++qq) {
        int rl = wm * 64 + mi * 16 + u4 * 4 + qq;       // 0..127; parity == global row&7
        int cs = u ^ (rl & 7);
        smem[tl * 8192 + rl * 64 + cs * 8 + o7] = f2bf(gelu_f(v[qq] + bbs[ni]));
      }
    }
  __syncthreads();
  size_t tb = ((size_t)mblk * (FFC >> 6) + (n0c >> 6)) * 8192;   // shorts
#pragma unroll
  for (int it = 0; it < 8; ++it) {
    int cc = tid + it * 256;                            // 2048 16B chunks = 32 KB
    *(bf16x8*)(h + tb + cc * 8) = *(const bf16x8*)(smem + cc * 8);
  }
}

// -- GEMM2: 128M x 256N, 8 waves, BK=64, 2-barrier; TILED A/B; supergroup-4 ---
__global__ __launch_bounds__(512, 4)
void gemm2_kernel(const short* __restrict__ h, const short* __restrict__ w2t,
                  const float* __restrict__ b2, const int* __restrict__ counts,
                  const int* __restrict__ tokg, const float* __restrict__ gateg,
                  float* __restrict__ out, int FFC, int chunk, int nchunks, int NPAN) {
  __shared__ __align__(16) short sA[128 * 64];          // 16 KB
  __shared__ __align__(16) short sB[256 * 64];          // 32 KB
  int L = xcd_chunk(blockIdx.x, gridDim.x);
  int sg = L / (4 * NPAN);
  int r  = L - sg * 4 * NPAN;
  int np = r >> 2, ml = r & 3;                          // panels outer, M inner-4
  int gm = sg * 4 + ml;
  int e, off, cnt, m0;
  if (!decode_expert(counts, gm, e, off, cnt, m0)) return;
  int n0 = np * 256;

  int mblk = (off + m0) >> 7;
  const char* Atile = (const char*)(h + (size_t)mblk * (FFC >> 6) * 8192);
  const int N64 = DMODEL >> 6;                          // 12
  const char* Btile = (const char*)(w2t + (((size_t)e * (DFF >> 6)) * N64 + (np << 2)) * 4096);
  const int ktg0 = chunk * (FFC >> 6);

  int tid = threadIdx.x, wid = tid >> 6, lane = tid & 63;
  int wm = wid >> 2, wn = wid & 3;
  int l15 = lane & 15, u4 = lane >> 4;

  f32x4 acc[4][4];
#pragma unroll
  for (int i = 0; i < 4; ++i)
#pragma unroll
    for (int j = 0; j < 4; ++j) acc[i][j] = (f32x4){0.f, 0.f, 0.f, 0.f};

  for (int kt = 0; kt < FFC / BK; ++kt) {
    const char* at = Atile + (size_t)kt * 16384;        // contiguous 16 KB
    const char* bt = Btile + (size_t)(ktg0 + kt) * (N64 * 8192);  // contiguous 32 KB
#pragma unroll
    for (int p = 0; p < 2; ++p) {                       // A: 1024 chunks
      int cc = tid + p * 512;
      gl_lds16(at + cc * 16, (char*)sA + (wid * 64 + p * 512) * 16);
    }
#pragma unroll
    for (int p = 0; p < 4; ++p) {                       // B: 2048 chunks
      int cc = tid + p * 512;
      gl_lds16(bt + cc * 16, (char*)sB + (wid * 64 + p * 512) * 16);
    }
    __syncthreads();
#pragma unroll
    for (int ks = 0; ks < 2; ++ks) {
      int u = ks * 4 + u4;
      int slot8 = (u ^ (l15 & 7)) << 3;
      bf16x8 af[4], bfr[4];
#pragma unroll
      for (int mi = 0; mi < 4; ++mi)
        af[mi] = *(const bf16x8*)&sA[(wm * 64 + mi * 16 + l15) * 64 + slot8];
#pragma unroll
      for (int ni = 0; ni < 4; ++ni)
        bfr[ni] = *(const bf16x8*)&sB[(wn * 64 + ni * 16 + l15) * 64 + slot8];
#pragma unroll
      for (int mi = 0; mi < 4; ++mi)
#pragma unroll
        for (int ni = 0; ni < 4; ++ni)
          acc[mi][ni] = __builtin_amdgcn_mfma_f32_16x16x32_bf16(af[mi], bfr[ni], acc[mi][ni], 0, 0, 0);
    }
    __syncthreads();
  }

#pragma unroll
  for (int ni = 0; ni < 4; ++ni) {
    int colg = n0 + wn * 64 + ni * 16 + l15;
    float bb = b2[e * DMODEL + colg];
#pragma unroll
    for (int mi = 0; mi < 4; ++mi) {
      f32x4 v = acc[mi][ni];
#pragma unroll
      for (int qq = 0; qq < 4; ++qq) {
        int ml2 = m0 + wm * 64 + mi * 16 + u4 * 4 + qq;
        if (ml2 < cnt) {
          int g = off + ml2;
          float* op = out + (size_t)tokg[g] * DMODEL + colg;
          float pv = v[qq];
          if (chunk == 0 && nchunks > 1) {
            *op = pv;
          } else if (chunk < nchunks - 1) {
            *op += pv;
          } else {
            float prev = (nchunks > 1) ? *op : 0.f;
            *op = (prev + pv + bb) * gateg[g];
          }
        }
      }
    }
  }
}

extern "C" void kernel_launch(void* const* d_in, const int* in_sizes, int n_in,
                              void* d_out, int out_size, void* d_ws, size_t ws_size,
                              hipStream_t stream) {
  (void)in_sizes; (void)n_in; (void)out_size;
  const float* x  = (const float*)d_in[0];
  const float* Wg = (const float*)d_in[1];
  const float* bg = (const float*)d_in[2];
  const float* W1 = (const float*)d_in[3];
  const float* b1 = (const float*)d_in[4];
  const float* W2 = (const float*)d_in[5];
  const float* b2 = (const float*)d_in[6];
  float* out = (float*)d_out;
  char* ws = (char*)d_ws;

  size_t cur = 0;
  auto take = [&](size_t bytes) -> size_t {
    cur = (cur + 255) & ~(size_t)255;
    size_t r = cur; cur += bytes; return r;
  };
  size_t o_counts = take(64);
  size_t o_perm  = take((size_t)NEXP * T_TOK * 4);
  size_t o_route = take((size_t)T_TOK * 4);
  size_t o_gate  = take((size_t)T_TOK * 4);
  size_t o_tokg  = take((size_t)(T_TOK + 512) * 4);
  size_t o_gateg = take((size_t)(T_TOK + 512) * 4);
  size_t o_w1t   = take((size_t)NEXP * (DMODEL / 64) * (DFF / 64) * 4096 * 2);
  size_t o_w2t   = take((size_t)NEXP * (DFF / 64) * (DMODEL / 64) * 4096 * 2);
  size_t o_xg    = take((size_t)MBLK_MAX * (DMODEL / 64) * 8192 * 2);
  cur = (cur + 255) & ~(size_t)255;
  size_t o_h = cur;

  int FFC = 256;
  const int cands[4] = {3072, 1536, 768, 256};
  for (int i = 0; i < 4; ++i) {
    size_t hbytes = (size_t)MBLK_MAX * (cands[i] >> 6) * 16384;  // tiled h
    if (o_h + hbytes <= ws_size) { FFC = cands[i]; break; }
  }

  int*   counts = (int*)(ws + o_counts);
  int*   perm   = (int*)(ws + o_perm);
  int*   routeb = (int*)(ws + o_route);
  float* gate   = (float*)(ws + o_gate);
  int*   tokg   = (int*)(ws + o_tokg);
  float* gateg  = (float*)(ws + o_gateg);
  short* w1t    = (short*)(ws + o_w1t);
  short* w2t    = (short*)(ws + o_w2t);
  short* xg     = (short*)(ws + o_xg);
  short* hbuf   = (short*)(ws + o_h);

  hipMemsetAsync(counts, 0, 64, stream);
  route_kernel<<<T_TOK / 4, 256, 0, stream>>>(x, Wg, bg, routeb, gate);
  bucket_kernel<<<T_TOK / 256, 256, 0, stream>>>(routeb, counts, perm);
  transpose_tiled_kernel<<<dim3(DMODEL / 64, DFF / 64, NEXP), 256, 0, stream>>>(W1, w1t, DMODEL, DFF);
  transpose_tiled_kernel<<<dim3(DFF / 64, DMODEL / 64, NEXP), 256, 0, stream>>>(W2, w2t, DFF, DMODEL);
  gather_kernel<<<dim3(T_TOK / 8, NEXP), 256, 0, stream>>>(x, counts, perm, gate, xg, tokg, gateg);

  int NC = DFF / FFC;
  int MBG = T_TOK / 128 + (NEXP - 1);                  // 131 max M-blocks (128-tiles)
  for (int c = 0; c < NC; ++c) {
    int NPAN1 = FFC / 128;
    int SGC1 = (MBG + 15) / 16;                        // 9 supergroups of 16
    gemm1_kernel<<<SGC1 * 16 * NPAN1, 256, 0, stream>>>(xg, w1t, b1, counts, hbuf, FFC, c, NPAN1);
    int NPAN2 = DMODEL / 256;                          // 3
    int SGC2 = (MBG + 3) / 4;                          // 33 supergroups of 4
    gemm2_kernel<<<SGC2 * 4 * NPAN2, 512, 0, stream>>>(hbuf, w2t, b2, counts, tokg, gateg, out, FFC, c, NC, NPAN2);
  }
}

// Round 13
// 266.069 us; speedup vs baseline: 1.0834x; 1.0039x over previous
//
#include <hip/hip_runtime.h>
#include <hip/hip_bf16.h>

#define T_TOK 16384
#define DMODEL 768
#define DFF 3072
#define NEXP 4
#define BK 64
#define MBLK_MAX (T_TOK / 128 + NEXP)   // 132

typedef __attribute__((ext_vector_type(8))) short bf16x8;
typedef __attribute__((ext_vector_type(4))) float f32x4;

__device__ __forceinline__ void gl_lds16(const void* g, void* l) {
  __builtin_amdgcn_global_load_lds(
      (const __attribute__((address_space(1))) unsigned int*)g,
      (__attribute__((address_space(3))) unsigned int*)l, 16, 0, 0);
}

__device__ __forceinline__ short f2bf(float f) {
  union { __hip_bfloat16 h; short s; } u;
  u.h = __float2bfloat16(f);            // compiler path -> v_cvt_pk_bf16_f32 capable
  return u.s;
}

__device__ __forceinline__ float gelu_f(float x) {
  // tanh-approx gelu: 0.5x(1+tanh(z)) == x * sigmoid(2z),
  // 2z = x * (c2 + c2*0.044715*x^2)
  const float c2 = 1.5957691216057308f;           // 2*sqrt(2/pi)
  const float k2 = 0.0713548353f;                 // c2 * 0.044715
  float t = x * x;
  float z2 = x * fmaf(k2, t, c2);
  return x * __frcp_rn(1.f + __expf(-z2));        // saturates correctly, no clamp
}

// tiled layouts (64x64-bf16 tiles, 4096 shorts; swizzle: 16B-chunk u of row r
// stored at u^(r&7)):
//   xg : [mblk][DMODEL/64][128][64]
//   w1t: [E][DMODEL/64][DFF/64][64][64]
//   w2t: [E][DFF/64][DMODEL/64][64][64]
//   h  : [mblk][FFC/64][128][64]

__device__ __forceinline__ int expert_aoff(const int* counts, int e) {
  int off = 0;
  for (int i = 0; i < e; ++i) off += (counts[i] + 127) & ~127;
  return off;
}

// ---------------- route: fp32 logits, softmax, argmax — NO atomics ----------
__global__ void route_kernel(const float* __restrict__ x, const float* __restrict__ Wg,
                             const float* __restrict__ bg, int* __restrict__ route,
                             float* __restrict__ gate) {
  int t = blockIdx.x * 4 + (threadIdx.x >> 6);
  int l = threadIdx.x & 63;
  const float* xr = x + (size_t)t * DMODEL;
  float s0 = 0.f, s1 = 0.f, s2 = 0.f, s3 = 0.f;
#pragma unroll
  for (int i = 0; i < DMODEL / 64; ++i) {
    int d = l + i * 64;
    float xv = xr[d];
    float4 w = *((const float4*)Wg + d);
    s0 += xv * w.x; s1 += xv * w.y; s2 += xv * w.z; s3 += xv * w.w;
  }
#pragma unroll
  for (int off = 32; off; off >>= 1) {
    s0 += __shfl_xor(s0, off);
    s1 += __shfl_xor(s1, off);
    s2 += __shfl_xor(s2, off);
    s3 += __shfl_xor(s3, off);
  }
  if (l == 0) {
    float lg[4] = { s0 + bg[0], s1 + bg[1], s2 + bg[2], s3 + bg[3] };
    int best = 0; float m = lg[0];
#pragma unroll
    for (int e = 1; e < 4; ++e) if (lg[e] > m) { m = lg[e]; best = e; }
    float s = 0.f;
#pragma unroll
    for (int e = 0; e < 4; ++e) s += __expf(lg[e] - m);
    route[t] = best;
    gate[t] = 1.0f / s;
  }
}

// ---- bucket: ballot histogram + LDS prefix, 4 atomics per block -------------
__global__ void bucket_kernel(const int* __restrict__ route, int* __restrict__ counts,
                              int* __restrict__ perm) {
  __shared__ int wcnt[4][NEXP];
  __shared__ int wpre[4][NEXP];
  __shared__ int base[NEXP];
  int tid = threadIdx.x;
  int t = blockIdx.x * 256 + tid;
  int w = tid >> 6, l = tid & 63;
  int r = route[t];
  int lanepre = 0;
  unsigned long long lower = (l == 0) ? 0ull : (~0ull >> (64 - l));
#pragma unroll
  for (int e = 0; e < NEXP; ++e) {
    unsigned long long m = __ballot(r == e);
    if (l == 0) wcnt[w][e] = (int)__popcll(m);
    if (r == e) lanepre = (int)__popcll(m & lower);
  }
  __syncthreads();
  if (tid < NEXP) {
    int s = 0;
#pragma unroll
    for (int ww = 0; ww < 4; ++ww) { wpre[ww][tid] = s; s += wcnt[ww][tid]; }
    base[tid] = atomicAdd(&counts[tid], s);
  }
  __syncthreads();
  int pos = base[r] + wpre[w][r] + lanepre;
  perm[r * T_TOK + pos] = t;
}

// --------- gather x rows -> expert-contiguous TILED bf16, swizzled -----------
__global__ void gather_kernel(const float* __restrict__ x, const int* __restrict__ counts,
                              const int* __restrict__ perm, const float* __restrict__ gate,
                              short* __restrict__ xg, int* __restrict__ tokg,
                              float* __restrict__ gateg) {
  int e = blockIdx.y;
  int cnt = counts[e];
  int pos = blockIdx.x * 8 + (threadIdx.x >> 5);
  if (pos >= cnt) return;
  int off = expert_aoff(counts, e);
  int t = perm[e * T_TOK + pos];
  int g = off + pos;
  int l = threadIdx.x & 31;
  const float* src = x + (size_t)t * DMODEL;
  size_t rbase = ((size_t)(g >> 7) * (DMODEL >> 6)) * 8192 + (g & 127) * 64;
  int sw = g & 7;
#pragma unroll
  for (int i = 0; i < 3; ++i) {
    int c = l + 32 * i;                              // 16B chunk index, 0..95
    float4 a = *((const float4*)src + c * 2);
    float4 b = *((const float4*)src + c * 2 + 1);
    bf16x8 v;
    v[0] = f2bf(a.x); v[1] = f2bf(a.y); v[2] = f2bf(a.z); v[3] = f2bf(a.w);
    v[4] = f2bf(b.x); v[5] = f2bf(b.y); v[6] = f2bf(b.z); v[7] = f2bf(b.w);
    int kt = c >> 3, u = c & 7;
    *(bf16x8*)(xg + rbase + (size_t)kt * 8192 + ((u ^ sw) << 3)) = v;
  }
  if (l == 0) { tokg[g] = t; gateg[g] = gate[t]; }
}

// --- transpose tiled: [K][N] fp32 -> [E][K/64][N/64][64][64] bf16 swizzled ---
__global__ void transpose_tiled_kernel(const float* __restrict__ src, short* __restrict__ dst,
                                       int K, int N) {
  __shared__ float lds[64 * 65];
  int e = blockIdx.z;
  int k0 = blockIdx.x * 64, n0 = blockIdx.y * 64;
  const float* s = src + (size_t)e * K * N;
#pragma unroll
  for (int i = 0; i < 16; ++i) {
    int idx = threadIdx.x + i * 256;
    int kk = idx >> 6, nn = idx & 63;
    lds[kk * 65 + nn] = s[(size_t)(k0 + kk) * N + n0 + nn];
  }
  __syncthreads();
  size_t tile = ((size_t)e * (K >> 6) + (k0 >> 6)) * (N >> 6) + (n0 >> 6);
  short* d = dst + tile * 4096;
#pragma unroll
  for (int i = 0; i < 2; ++i) {
    int cid = threadIdx.x + i * 256;
    int nn = cid >> 3, uu = cid & 7;                // row nn (N-dir), chunk uu (K-dir)
    int n = n0 + nn;
    bf16x8 v;
#pragma unroll
    for (int j = 0; j < 8; ++j) v[j] = f2bf(lds[(uu * 8 + j) * 65 + nn]);
    int cs = uu ^ (n & 7);
    *(bf16x8*)(d + nn * 64 + cs * 8) = v;
  }
}

// XCD-bijective chunked decode (m204)
__device__ __forceinline__ int xcd_chunk(int orig, int nwg) {
  int q = nwg >> 3, r = nwg & 7, xcd = orig & 7;
  return (xcd < r ? xcd * (q + 1) : r * (q + 1) + (xcd - r) * q) + (orig >> 3);
}

// expert decode from linear M-block index (tile height = 128)
__device__ __forceinline__ bool decode_expert(const int* counts, int gm,
                                              int& e, int& off, int& cnt, int& m0) {
  int c0 = counts[0], c1 = counts[1], c2 = counts[2], c3 = counts[3];
  int mb0 = (c0 + 127) >> 7, mb1 = (c1 + 127) >> 7, mb2 = (c2 + 127) >> 7, mb3 = (c3 + 127) >> 7;
  int o1 = (c0 + 127) & ~127, o2 = o1 + ((c1 + 127) & ~127), o3 = o2 + ((c2 + 127) & ~127);
  if (gm < mb0)                        { e = 0; off = 0;  cnt = c0; m0 = gm << 7; return true; }
  if (gm < mb0 + mb1)                  { e = 1; off = o1; cnt = c1; m0 = (gm - mb0) << 7; return true; }
  if (gm < mb0 + mb1 + mb2)            { e = 2; off = o2; cnt = c2; m0 = (gm - mb0 - mb1) << 7; return true; }
  if (gm < mb0 + mb1 + mb2 + mb3)      { e = 3; off = o3; cnt = c3; m0 = (gm - mb0 - mb1 - mb2) << 7; return true; }
  return false;
}

// --- GEMM1: 128x128, 4 waves, BK=64, 2-barrier; TILED A/B; supergroup-16 -----
__global__ __launch_bounds__(256, 4)
void gemm1_kernel(const short* __restrict__ xg, const short* __restrict__ w1t,
                  const float* __restrict__ b1, const int* __restrict__ counts,
                  short* __restrict__ h, int FFC, int chunk, int NPAN) {
  __shared__ __align__(16) short smem[16384];           // 32 KB: sA|sB, reused as bounce
  short* sA = smem;                                     // 16 KB (128 x 64)
  short* sB = smem + 8192;                              // 16 KB (2 x 64 x 64 tiles)
  int L = xcd_chunk(blockIdx.x, gridDim.x);
  int sg = L / (16 * NPAN);
  int r  = L - sg * 16 * NPAN;
  int np = r >> 4, ml = r & 15;                         // panels outer, M inner-16
  int gm = sg * 16 + ml;
  int e, off, cnt, m0;
  if (!decode_expert(counts, gm, e, off, cnt, m0)) return;
  (void)cnt;
  int n0c = np * 128;
  int n0g = chunk * FFC + n0c;

  int mblk = (off + m0) >> 7;
  const char* Atile = (const char*)(xg + (size_t)mblk * (DMODEL >> 6) * 8192);
  const int NB = DFF >> 6;                              // 48
  const char* Btile = (const char*)(w1t + (((size_t)e * (DMODEL >> 6)) * NB + (n0g >> 6)) * 4096);

  int tid = threadIdx.x, wid = tid >> 6, lane = tid & 63;
  int wm = wid >> 1, wn = wid & 1;
  int l15 = lane & 15, u4 = lane >> 4;

  f32x4 acc[4][4];
#pragma unroll
  for (int i = 0; i < 4; ++i)
#pragma unroll
    for (int j = 0; j < 4; ++j) acc[i][j] = (f32x4){0.f, 0.f, 0.f, 0.f};

  for (int kt = 0; kt < DMODEL / BK; ++kt) {
    const char* at = Atile + (size_t)kt * 16384;        // contiguous 16 KB
    const char* bt = Btile + (size_t)kt * (NB * 8192);  // contiguous 16 KB (2 tiles)
#pragma unroll
    for (int p = 0; p < 4; ++p) {
      int cc = tid + p * 256;                           // 1024 chunks each
      gl_lds16(at + cc * 16, (char*)sA + (wid * 64 + p * 256) * 16);
      gl_lds16(bt + cc * 16, (char*)sB + (wid * 64 + p * 256) * 16);
    }
    __syncthreads();
#pragma unroll
    for (int ks = 0; ks < 2; ++ks) {
      int u = ks * 4 + u4;
      int slot8 = (u ^ (l15 & 7)) << 3;
      bf16x8 af[4], bfr[4];
#pragma unroll
      for (int mi = 0; mi < 4; ++mi)
        af[mi] = *(const bf16x8*)&sA[(wm * 64 + mi * 16 + l15) * 64 + slot8];
#pragma unroll
      for (int ni = 0; ni < 4; ++ni) {
        int col = wn * 64 + ni * 16 + l15;              // 0..127
        bfr[ni] = *(const bf16x8*)&sB[(col >> 6) * 4096 + (col & 63) * 64 + slot8];
      }
#pragma unroll
      for (int mi = 0; mi < 4; ++mi)
#pragma unroll
        for (int ni = 0; ni < 4; ++ni)
          acc[mi][ni] = __builtin_amdgcn_mfma_f32_16x16x32_bf16(af[mi], bfr[ni], acc[mi][ni], 0, 0, 0);
    }
    __syncthreads();
  }

  // ---- epilogue: gelu+bias -> 32KB bounce in TILED h layout -> linear copy --
  float bbs[4];
#pragma unroll
  for (int ni = 0; ni < 4; ++ni) bbs[ni] = b1[e * DFF + n0g + wn * 64 + ni * 16 + l15];
#pragma unroll
  for (int mi = 0; mi < 4; ++mi)
#pragma unroll
    for (int ni = 0; ni < 4; ++ni) {
      f32x4 v = acc[mi][ni];
      int col = wn * 64 + ni * 16 + l15;                // 0..127
      int tl = col >> 6, wc = col & 63;
      int u = wc >> 3, o7 = wc & 7;
#pragma unroll
      for (int qq = 0; qq < 4; ++qq) {
        int rl = wm * 64 + mi * 16 + u4 * 4 + qq;       // 0..127; parity == global row&7
        int cs = u ^ (rl & 7);
        smem[tl * 8192 + rl * 64 + cs * 8 + o7] = f2bf(gelu_f(v[qq] + bbs[ni]));
      }
    }
  __syncthreads();
  size_t tb = ((size_t)mblk * (FFC >> 6) + (n0c >> 6)) * 8192;   // shorts
#pragma unroll
  for (int it = 0; it < 8; ++it) {
    int cc = tid + it * 256;                            // 2048 16B chunks = 32 KB
    *(bf16x8*)(h + tb + cc * 8) = *(const bf16x8*)(smem + cc * 8);
  }
}

// -- GEMM2: 128M x 256N, 8 waves, BK=64, 2-barrier; TILED A/B; supergroup-4 ---
__global__ __launch_bounds__(512, 4)
void gemm2_kernel(const short* __restrict__ h, const short* __restrict__ w2t,
                  const float* __restrict__ b2, const int* __restrict__ counts,
                  const int* __restrict__ tokg, const float* __restrict__ gateg,
                  float* __restrict__ out, int FFC, int chunk, int nchunks, int NPAN) {
  __shared__ __align__(16) short sA[128 * 64];          // 16 KB
  __shared__ __align__(16) short sB[256 * 64];          // 32 KB
  int L = xcd_chunk(blockIdx.x, gridDim.x);
  int sg = L / (4 * NPAN);
  int r  = L - sg * 4 * NPAN;
  int np = r >> 2, ml = r & 3;                          // panels outer, M inner-4
  int gm = sg * 4 + ml;
  int e, off, cnt, m0;
  if (!decode_expert(counts, gm, e, off, cnt, m0)) return;
  int n0 = np * 256;

  int mblk = (off + m0) >> 7;
  const char* Atile = (const char*)(h + (size_t)mblk * (FFC >> 6) * 8192);
  const int N64 = DMODEL >> 6;                          // 12
  const char* Btile = (const char*)(w2t + (((size_t)e * (DFF >> 6)) * N64 + (np << 2)) * 4096);
  const int ktg0 = chunk * (FFC >> 6);

  int tid = threadIdx.x, wid = tid >> 6, lane = tid & 63;
  int wm = wid >> 2, wn = wid & 3;
  int l15 = lane & 15, u4 = lane >> 4;

  f32x4 acc[4][4];
#pragma unroll
  for (int i = 0; i < 4; ++i)
#pragma unroll
    for (int j = 0; j < 4; ++j) acc[i][j] = (f32x4){0.f, 0.f, 0.f, 0.f};

  for (int kt = 0; kt < FFC / BK; ++kt) {
    const char* at = Atile + (size_t)kt * 16384;        // contiguous 16 KB
    const char* bt = Btile + (size_t)(ktg0 + kt) * (N64 * 8192);  // contiguous 32 KB
#pragma unroll
    for (int p = 0; p < 2; ++p) {                       // A: 1024 chunks
      int cc = tid + p * 512;
      gl_lds16(at + cc * 16, (char*)sA + (wid * 64 + p * 512) * 16);
    }
#pragma unroll
    for (int p = 0; p < 4; ++p) {                       // B: 2048 chunks
      int cc = tid + p * 512;
      gl_lds16(bt + cc * 16, (char*)sB + (wid * 64 + p * 512) * 16);
    }
    __syncthreads();
#pragma unroll
    for (int ks = 0; ks < 2; ++ks) {
      int u = ks * 4 + u4;
      int slot8 = (u ^ (l15 & 7)) << 3;
      bf16x8 af[4], bfr[4];
#pragma unroll
      for (int mi = 0; mi < 4; ++mi)
        af[mi] = *(const bf16x8*)&sA[(wm * 64 + mi * 16 + l15) * 64 + slot8];
#pragma unroll
      for (int ni = 0; ni < 4; ++ni)
        bfr[ni] = *(const bf16x8*)&sB[(wn * 64 + ni * 16 + l15) * 64 + slot8];
#pragma unroll
      for (int mi = 0; mi < 4; ++mi)
#pragma unroll
        for (int ni = 0; ni < 4; ++ni)
          acc[mi][ni] = __builtin_amdgcn_mfma_f32_16x16x32_bf16(af[mi], bfr[ni], acc[mi][ni], 0, 0, 0);
    }
    __syncthreads();
  }

#pragma unroll
  for (int ni = 0; ni < 4; ++ni) {
    int colg = n0 + wn * 64 + ni * 16 + l15;
    float bb = b2[e * DMODEL + colg];
#pragma unroll
    for (int mi = 0; mi < 4; ++mi) {
      f32x4 v = acc[mi][ni];
#pragma unroll
      for (int qq = 0; qq < 4; ++qq) {
        int ml2 = m0 + wm * 64 + mi * 16 + u4 * 4 + qq;
        if (ml2 < cnt) {
          int g = off + ml2;
          float* op = out + (size_t)tokg[g] * DMODEL + colg;
          float pv = v[qq];
          if (chunk == 0 && nchunks > 1) {
            *op = pv;
          } else if (chunk < nchunks - 1) {
            *op += pv;
          } else {
            float prev = (nchunks > 1) ? *op : 0.f;
            *op = (prev + pv + bb) * gateg[g];
          }
        }
      }
    }
  }
}

extern "C" void kernel_launch(void* const* d_in, const int* in_sizes, int n_in,
                              void* d_out, int out_size, void* d_ws, size_t ws_size,
                              hipStream_t stream) {
  (void)in_sizes; (void)n_in; (void)out_size;
  const float* x  = (const float*)d_in[0];
  const float* Wg = (const float*)d_in[1];
  const float* bg = (const float*)d_in[2];
  const float* W1 = (const float*)d_in[3];
  const float* b1 = (const float*)d_in[4];
  const float* W2 = (const float*)d_in[5];
  const float* b2 = (const float*)d_in[6];
  float* out = (float*)d_out;
  char* ws = (char*)d_ws;

  size_t cur = 0;
  auto take = [&](size_t bytes) -> size_t {
    cur = (cur + 255) & ~(size_t)255;
    size_t r = cur; cur += bytes; return r;
  };
  size_t o_counts = take(64);
  size_t o_perm  = take((size_t)NEXP * T_TOK * 4);
  size_t o_route = take((size_t)T_TOK * 4);
  size_t o_gate  = take((size_t)T_TOK * 4);
  size_t o_tokg  = take((size_t)(T_TOK + 512) * 4);
  size_t o_gateg = take((size_t)(T_TOK + 512) * 4);
  size_t o_w1t   = take((size_t)NEXP * (DMODEL / 64) * (DFF / 64) * 4096 * 2);
  size_t o_w2t   = take((size_t)NEXP * (DFF / 64) * (DMODEL / 64) * 4096 * 2);
  size_t o_xg    = take((size_t)MBLK_MAX * (DMODEL / 64) * 8192 * 2);
  cur = (cur + 255) & ~(size_t)255;
  size_t o_h = cur;

  int FFC = 256;
  const int cands[4] = {3072, 1536, 768, 256};
  for (int i = 0; i < 4; ++i) {
    size_t hbytes = (size_t)MBLK_MAX * (cands[i] >> 6) * 16384;  // tiled h
    if (o_h + hbytes <= ws_size) { FFC = cands[i]; break; }
  }

  int*   counts = (int*)(ws + o_counts);
  int*   perm   = (int*)(ws + o_perm);
  int*   routeb = (int*)(ws + o_route);
  float* gate   = (float*)(ws + o_gate);
  int*   tokg   = (int*)(ws + o_tokg);
  float* gateg  = (float*)(ws + o_gateg);
  short* w1t    = (short*)(ws + o_w1t);
  short* w2t    = (short*)(ws + o_w2t);
  short* xg     = (short*)(ws + o_xg);
  short* hbuf   = (short*)(ws + o_h);

  hipMemsetAsync(counts, 0, 64, stream);
  route_kernel<<<T_TOK / 4, 256, 0, stream>>>(x, Wg, bg, routeb, gate);
  bucket_kernel<<<T_TOK / 256, 256, 0, stream>>>(routeb, counts, perm);
  transpose_tiled_kernel<<<dim3(DMODEL / 64, DFF / 64, NEXP), 256, 0, stream>>>(W1, w1t, DMODEL, DFF);
  transpose_tiled_kernel<<<dim3(DFF / 64, DMODEL / 64, NEXP), 256, 0, stream>>>(W2, w2t, DFF, DMODEL);
  gather_kernel<<<dim3(T_TOK / 8, NEXP), 256, 0, stream>>>(x, counts, perm, gate, xg, tokg, gateg);

  int NC = DFF / FFC;
  int MBG = T_TOK / 128 + (NEXP - 1);                  // 131 max M-blocks (128-tiles)
  for (int c = 0; c < NC; ++c) {
    int NPAN1 = FFC / 128;
    int SGC1 = (MBG + 15) / 16;                        // 9 supergroups of 16
    gemm1_kernel<<<SGC1 * 16 * NPAN1, 256, 0, stream>>>(xg, w1t, b1, counts, hbuf, FFC, c, NPAN1);
    int NPAN2 = DMODEL / 256;                          // 3
    int SGC2 = (MBG + 3) / 4;                          // 33 supergroups of 4
    gemm2_kernel<<<SGC2 * 4 * NPAN2, 512, 0, stream>>>(hbuf, w2t, b2, counts, tokg, gateg, out, FFC, c, NC, NPAN2);
  }
}

// Round 14
// 261.334 us; speedup vs baseline: 1.1030x; 1.0181x over previous
//
#include <hip/hip_runtime.h>
#include <hip/hip_bf16.h>

#define T_TOK 16384
#define DMODEL 768
#define DFF 3072
#define NEXP 4
#define BK 64
#define MBLK_MAX (T_TOK / 128 + NEXP)   // 132

typedef __attribute__((ext_vector_type(8))) short bf16x8;
typedef __attribute__((ext_vector_type(4))) float f32x4;

__device__ __forceinline__ void gl_lds16(const void* g, void* l) {
  __builtin_amdgcn_global_load_lds(
      (const __attribute__((address_space(1))) unsigned int*)g,
      (__attribute__((address_space(3))) unsigned int*)l, 16, 0, 0);
}

__device__ __forceinline__ short f2bf(float f) {
  union { __hip_bfloat16 h; short s; } u;
  u.h = __float2bfloat16(f);
  return u.s;
}

__device__ __forceinline__ float gelu_f(float x) {
  // tanh-approx gelu: 0.5x(1+tanh(z)) == x * sigmoid(2z), 2z = x*(c2 + c2*0.044715*x^2)
  const float c2 = 1.5957691216057308f;
  const float k2 = 0.0713548353f;
  float t = x * x;
  float z2 = x * fmaf(k2, t, c2);
  return x * __frcp_rn(1.f + __expf(-z2));
}

// tiled layouts (64x64-bf16 tiles, 4096 shorts; swizzle: 16B-chunk u of row r
// stored at u^(r&7)):
//   xg : [mblk][DMODEL/64][128][64]
//   w1t: [E][DMODEL/64][DFF/64][64][64]
//   w2t: [E][DFF/64][DMODEL/64][64][64]
//   h  : [mblk][FFC/64][128][64]

__device__ __forceinline__ int expert_aoff(const int* counts, int e) {
  int off = 0;
  for (int i = 0; i < e; ++i) off += (counts[i] + 127) & ~127;
  return off;
}

// ---------------- route: fp32 logits, softmax, argmax — NO atomics ----------
__global__ void route_kernel(const float* __restrict__ x, const float* __restrict__ Wg,
                             const float* __restrict__ bg, int* __restrict__ route,
                             float* __restrict__ gate) {
  int t = blockIdx.x * 4 + (threadIdx.x >> 6);
  int l = threadIdx.x & 63;
  const float* xr = x + (size_t)t * DMODEL;
  float s0 = 0.f, s1 = 0.f, s2 = 0.f, s3 = 0.f;
#pragma unroll
  for (int i = 0; i < DMODEL / 64; ++i) {
    int d = l + i * 64;
    float xv = xr[d];
    float4 w = *((const float4*)Wg + d);
    s0 += xv * w.x; s1 += xv * w.y; s2 += xv * w.z; s3 += xv * w.w;
  }
#pragma unroll
  for (int off = 32; off; off >>= 1) {
    s0 += __shfl_xor(s0, off);
    s1 += __shfl_xor(s1, off);
    s2 += __shfl_xor(s2, off);
    s3 += __shfl_xor(s3, off);
  }
  if (l == 0) {
    float lg[4] = { s0 + bg[0], s1 + bg[1], s2 + bg[2], s3 + bg[3] };
    int best = 0; float m = lg[0];
#pragma unroll
    for (int e = 1; e < 4; ++e) if (lg[e] > m) { m = lg[e]; best = e; }
    float s = 0.f;
#pragma unroll
    for (int e = 0; e < 4; ++e) s += __expf(lg[e] - m);
    route[t] = best;
    gate[t] = 1.0f / s;
  }
}

// ---- bucket: ballot histogram + LDS prefix, 4 atomics per block -------------
__global__ void bucket_kernel(const int* __restrict__ route, int* __restrict__ counts,
                              int* __restrict__ perm) {
  __shared__ int wcnt[4][NEXP];
  __shared__ int wpre[4][NEXP];
  __shared__ int base[NEXP];
  int tid = threadIdx.x;
  int t = blockIdx.x * 256 + tid;
  int w = tid >> 6, l = tid & 63;
  int r = route[t];
  int lanepre = 0;
  unsigned long long lower = (l == 0) ? 0ull : (~0ull >> (64 - l));
#pragma unroll
  for (int e = 0; e < NEXP; ++e) {
    unsigned long long m = __ballot(r == e);
    if (l == 0) wcnt[w][e] = (int)__popcll(m);
    if (r == e) lanepre = (int)__popcll(m & lower);
  }
  __syncthreads();
  if (tid < NEXP) {
    int s = 0;
#pragma unroll
    for (int ww = 0; ww < 4; ++ww) { wpre[ww][tid] = s; s += wcnt[ww][tid]; }
    base[tid] = atomicAdd(&counts[tid], s);
  }
  __syncthreads();
  int pos = base[r] + wpre[w][r] + lanepre;
  perm[r * T_TOK + pos] = t;
}

// --------- gather x rows -> expert-contiguous TILED bf16, swizzled -----------
__global__ void gather_kernel(const float* __restrict__ x, const int* __restrict__ counts,
                              const int* __restrict__ perm, const float* __restrict__ gate,
                              short* __restrict__ xg, int* __restrict__ tokg,
                              float* __restrict__ gateg) {
  int e = blockIdx.y;
  int cnt = counts[e];
  int pos = blockIdx.x * 8 + (threadIdx.x >> 5);
  if (pos >= cnt) return;
  int off = expert_aoff(counts, e);
  int t = perm[e * T_TOK + pos];
  int g = off + pos;
  int l = threadIdx.x & 31;
  const float* src = x + (size_t)t * DMODEL;
  size_t rbase = ((size_t)(g >> 7) * (DMODEL >> 6)) * 8192 + (g & 127) * 64;
  int sw = g & 7;
#pragma unroll
  for (int i = 0; i < 3; ++i) {
    int c = l + 32 * i;                              // 16B chunk index, 0..95
    float4 a = *((const float4*)src + c * 2);
    float4 b = *((const float4*)src + c * 2 + 1);
    bf16x8 v;
    v[0] = f2bf(a.x); v[1] = f2bf(a.y); v[2] = f2bf(a.z); v[3] = f2bf(a.w);
    v[4] = f2bf(b.x); v[5] = f2bf(b.y); v[6] = f2bf(b.z); v[7] = f2bf(b.w);
    int kt = c >> 3, u = c & 7;
    *(bf16x8*)(xg + rbase + (size_t)kt * 8192 + ((u ^ sw) << 3)) = v;
  }
  if (l == 0) { tokg[g] = t; gateg[g] = gate[t]; }
}

// --- transpose tiled: [K][N] fp32 -> [E][K/64][N/64][64][64] bf16 swizzled ---
__global__ void transpose_tiled_kernel(const float* __restrict__ src, short* __restrict__ dst,
                                       int K, int N) {
  __shared__ float lds[64 * 65];
  int e = blockIdx.z;
  int k0 = blockIdx.x * 64, n0 = blockIdx.y * 64;
  const float* s = src + (size_t)e * K * N;
#pragma unroll
  for (int i = 0; i < 16; ++i) {
    int idx = threadIdx.x + i * 256;
    int kk = idx >> 6, nn = idx & 63;
    lds[kk * 65 + nn] = s[(size_t)(k0 + kk) * N + n0 + nn];
  }
  __syncthreads();
  size_t tile = ((size_t)e * (K >> 6) + (k0 >> 6)) * (N >> 6) + (n0 >> 6);
  short* d = dst + tile * 4096;
#pragma unroll
  for (int i = 0; i < 2; ++i) {
    int cid = threadIdx.x + i * 256;
    int nn = cid >> 3, uu = cid & 7;                // row nn (N-dir), chunk uu (K-dir)
    int n = n0 + nn;
    bf16x8 v;
#pragma unroll
    for (int j = 0; j < 8; ++j) v[j] = f2bf(lds[(uu * 8 + j) * 65 + nn]);
    int cs = uu ^ (n & 7);
    *(bf16x8*)(d + nn * 64 + cs * 8) = v;
  }
}

// XCD-bijective chunked decode (m204)
__device__ __forceinline__ int xcd_chunk(int orig, int nwg) {
  int q = nwg >> 3, r = nwg & 7, xcd = orig & 7;
  return (xcd < r ? xcd * (q + 1) : r * (q + 1) + (xcd - r) * q) + (orig >> 3);
}

// expert decode from linear M-block index (tile height = 128)
__device__ __forceinline__ bool decode_expert(const int* counts, int gm,
                                              int& e, int& off, int& cnt, int& m0) {
  int c0 = counts[0], c1 = counts[1], c2 = counts[2], c3 = counts[3];
  int mb0 = (c0 + 127) >> 7, mb1 = (c1 + 127) >> 7, mb2 = (c2 + 127) >> 7, mb3 = (c3 + 127) >> 7;
  int o1 = (c0 + 127) & ~127, o2 = o1 + ((c1 + 127) & ~127), o3 = o2 + ((c2 + 127) & ~127);
  if (gm < mb0)                        { e = 0; off = 0;  cnt = c0; m0 = gm << 7; return true; }
  if (gm < mb0 + mb1)                  { e = 1; off = o1; cnt = c1; m0 = (gm - mb0) << 7; return true; }
  if (gm < mb0 + mb1 + mb2)            { e = 2; off = o2; cnt = c2; m0 = (gm - mb0 - mb1) << 7; return true; }
  if (gm < mb0 + mb1 + mb2 + mb3)      { e = 3; off = o3; cnt = c3; m0 = (gm - mb0 - mb1 - mb2) << 7; return true; }
  return false;
}

// expert decode for 256-row tiles; hasHi = second 128-block belongs to expert
__device__ __forceinline__ bool decode_expert256(const int* counts, int gm,
                                                 int& e, int& off, int& m0, bool& hasHi) {
  int c0 = counts[0], c1 = counts[1], c2 = counts[2], c3 = counts[3];
  int mb0 = (c0 + 127) >> 7, mb1 = (c1 + 127) >> 7, mb2 = (c2 + 127) >> 7, mb3 = (c3 + 127) >> 7;
  int t0 = (mb0 + 1) >> 1, t1 = (mb1 + 1) >> 1, t2 = (mb2 + 1) >> 1, t3 = (mb3 + 1) >> 1;
  int o1 = (c0 + 127) & ~127, o2 = o1 + ((c1 + 127) & ~127), o3 = o2 + ((c2 + 127) & ~127);
  int lt, mb;
  if (gm < t0)                   { e = 0; off = 0;  lt = gm; mb = mb0; }
  else if (gm < t0 + t1)         { e = 1; off = o1; lt = gm - t0; mb = mb1; }
  else if (gm < t0 + t1 + t2)    { e = 2; off = o2; lt = gm - t0 - t1; mb = mb2; }
  else if (gm < t0 + t1 + t2 + t3) { e = 3; off = o3; lt = gm - t0 - t1 - t2; mb = mb3; }
  else return false;
  m0 = lt << 8;
  hasHi = (lt * 2 + 1) < mb;
  return true;
}

// --- GEMM1: 256M x 128N, 8 waves (4Mx2N), BK=64, 2-barrier; TILED A/B --------
__global__ __launch_bounds__(512, 4)
void gemm1_kernel(const short* __restrict__ xg, const short* __restrict__ w1t,
                  const float* __restrict__ b1, const int* __restrict__ counts,
                  short* __restrict__ h, int FFC, int chunk, int NPAN) {
  __shared__ __align__(16) short smem[24576];           // 48 KB
  short* sA = smem;                                     // 32 KB (256 x 64)
  short* sB = smem + 16384;                             // 16 KB (2 x 64x64 tiles)
  int L = xcd_chunk(blockIdx.x, gridDim.x);
  int sg = L / (8 * NPAN);
  int r  = L - sg * 8 * NPAN;
  int np = r >> 3, ml = r & 7;                          // panels outer, M inner-8
  int gm = sg * 8 + ml;
  int e, off, m0; bool hasHi;
  if (!decode_expert256(counts, gm, e, off, m0, hasHi)) return;
  int n0c = np * 128;
  int n0g = chunk * FFC + n0c;

  int mblk = (off + m0) >> 7;                           // first 128-block
  const char* At0 = (const char*)(xg + (size_t)mblk * (DMODEL >> 6) * 8192);
  const char* At1 = (const char*)(xg + (size_t)(mblk + 1) * (DMODEL >> 6) * 8192);
  const int NB = DFF >> 6;                              // 48
  const char* Btile = (const char*)(w1t + (((size_t)e * (DMODEL >> 6)) * NB + (n0g >> 6)) * 4096);

  int tid = threadIdx.x, wid = tid >> 6, lane = tid & 63;
  int wm = wid >> 1, wn = wid & 1;                      // 4M x 2N waves
  int l15 = lane & 15, u4 = lane >> 4;

  f32x4 acc[4][4];
#pragma unroll
  for (int i = 0; i < 4; ++i)
#pragma unroll
    for (int j = 0; j < 4; ++j) acc[i][j] = (f32x4){0.f, 0.f, 0.f, 0.f};

  for (int kt = 0; kt < DMODEL / BK; ++kt) {
    const char* a0 = At0 + (size_t)kt * 16384;          // contiguous 16 KB (rows 0-127)
    const char* a1 = At1 + (size_t)kt * 16384;          // contiguous 16 KB (rows 128-255)
    const char* bt = Btile + (size_t)kt * (NB * 8192);  // contiguous 16 KB (2 tiles)
#pragma unroll
    for (int p = 0; p < 2; ++p) {
      int cc = tid + p * 512;                           // 1024 chunks each region
      gl_lds16(a0 + cc * 16, (char*)sA + cc * 16);
      gl_lds16(a1 + cc * 16, (char*)sA + 16384 + cc * 16);
      gl_lds16(bt + cc * 16, (char*)sB + cc * 16);
    }
    __syncthreads();
#pragma unroll
    for (int ks = 0; ks < 2; ++ks) {
      int u = ks * 4 + u4;
      int slot8 = (u ^ (l15 & 7)) << 3;
      bf16x8 af[4], bfr[4];
#pragma unroll
      for (int mi = 0; mi < 4; ++mi) {
        int row = wm * 64 + mi * 16 + l15;              // 0..255
        af[mi] = *(const bf16x8*)&sA[row * 64 + slot8];
      }
#pragma unroll
      for (int ni = 0; ni < 4; ++ni) {
        int col = wn * 64 + ni * 16 + l15;              // 0..127
        bfr[ni] = *(const bf16x8*)&sB[(col >> 6) * 4096 + (col & 63) * 64 + slot8];
      }
#pragma unroll
      for (int mi = 0; mi < 4; ++mi)
#pragma unroll
        for (int ni = 0; ni < 4; ++ni)
          acc[mi][ni] = __builtin_amdgcn_mfma_f32_16x16x32_bf16(af[mi], bfr[ni], acc[mi][ni], 0, 0, 0);
    }
    __syncthreads();
  }

  // ---- epilogue: two 128-row halves through 32KB bounce (tiled h layout) ----
  float bbs[4];
#pragma unroll
  for (int ni = 0; ni < 4; ++ni) bbs[ni] = b1[e * DFF + n0g + wn * 64 + ni * 16 + l15];
#pragma unroll
  for (int half = 0; half < 2; ++half) {
    if ((wm >> 1) == half) {                            // waves owning this half
#pragma unroll
      for (int mi = 0; mi < 4; ++mi)
#pragma unroll
        for (int ni = 0; ni < 4; ++ni) {
          f32x4 v = acc[mi][ni];
          int col = wn * 64 + ni * 16 + l15;            // 0..127
          int tl = col >> 6, wc = col & 63;
          int u = wc >> 3, o7 = wc & 7;
#pragma unroll
          for (int qq = 0; qq < 4; ++qq) {
            int rl = (wm & 1) * 64 + mi * 16 + u4 * 4 + qq;  // 0..127 in half
            int cs = u ^ (rl & 7);
            smem[tl * 8192 + rl * 64 + cs * 8 + o7] = f2bf(gelu_f(v[qq] + bbs[ni]));
          }
        }
    }
    __syncthreads();
    if (half == 0 || hasHi) {
      size_t tb = ((size_t)(mblk + half) * (FFC >> 6) + (n0c >> 6)) * 8192;
#pragma unroll
      for (int it = 0; it < 4; ++it) {
        int cc = tid + it * 512;                        // 2048 16B chunks = 32 KB
        *(bf16x8*)(h + tb + cc * 8) = *(const bf16x8*)(smem + cc * 8);
      }
    }
    __syncthreads();
  }
}

// -- GEMM2: 128M x 256N, 8 waves, BK=64, 2-barrier; TILED A/B; supergroup-4 ---
__global__ __launch_bounds__(512, 4)
void gemm2_kernel(const short* __restrict__ h, const short* __restrict__ w2t,
                  const float* __restrict__ b2, const int* __restrict__ counts,
                  const int* __restrict__ tokg, const float* __restrict__ gateg,
                  float* __restrict__ out, int FFC, int chunk, int nchunks, int NPAN) {
  __shared__ __align__(16) short sA[128 * 64];          // 16 KB
  __shared__ __align__(16) short sB[256 * 64];          // 32 KB
  int L = xcd_chunk(blockIdx.x, gridDim.x);
  int sg = L / (4 * NPAN);
  int r  = L - sg * 4 * NPAN;
  int np = r >> 2, ml = r & 3;                          // panels outer, M inner-4
  int gm = sg * 4 + ml;
  int e, off, cnt, m0;
  if (!decode_expert(counts, gm, e, off, cnt, m0)) return;
  int n0 = np * 256;

  int mblk = (off + m0) >> 7;
  const char* Atile = (const char*)(h + (size_t)mblk * (FFC >> 6) * 8192);
  const int N64 = DMODEL >> 6;                          // 12
  const char* Btile = (const char*)(w2t + (((size_t)e * (DFF >> 6)) * N64 + (np << 2)) * 4096);
  const int ktg0 = chunk * (FFC >> 6);

  int tid = threadIdx.x, wid = tid >> 6, lane = tid & 63;
  int wm = wid >> 2, wn = wid & 3;
  int l15 = lane & 15, u4 = lane >> 4;

  f32x4 acc[4][4];
#pragma unroll
  for (int i = 0; i < 4; ++i)
#pragma unroll
    for (int j = 0; j < 4; ++j) acc[i][j] = (f32x4){0.f, 0.f, 0.f, 0.f};

  for (int kt = 0; kt < FFC / BK; ++kt) {
    const char* at = Atile + (size_t)kt * 16384;        // contiguous 16 KB
    const char* bt = Btile + (size_t)(ktg0 + kt) * (N64 * 8192);  // contiguous 32 KB
#pragma unroll
    for (int p = 0; p < 2; ++p) {                       // A: 1024 chunks
      int cc = tid + p * 512;
      gl_lds16(at + cc * 16, (char*)sA + (wid * 64 + p * 512) * 16);
    }
#pragma unroll
    for (int p = 0; p < 4; ++p) {                       // B: 2048 chunks
      int cc = tid + p * 512;
      gl_lds16(bt + cc * 16, (char*)sB + (wid * 64 + p * 512) * 16);
    }
    __syncthreads();
#pragma unroll
    for (int ks = 0; ks < 2; ++ks) {
      int u = ks * 4 + u4;
      int slot8 = (u ^ (l15 & 7)) << 3;
      bf16x8 af[4], bfr[4];
#pragma unroll
      for (int mi = 0; mi < 4; ++mi)
        af[mi] = *(const bf16x8*)&sA[(wm * 64 + mi * 16 + l15) * 64 + slot8];
#pragma unroll
      for (int ni = 0; ni < 4; ++ni)
        bfr[ni] = *(const bf16x8*)&sB[(wn * 64 + ni * 16 + l15) * 64 + slot8];
#pragma unroll
      for (int mi = 0; mi < 4; ++mi)
#pragma unroll
        for (int ni = 0; ni < 4; ++ni)
          acc[mi][ni] = __builtin_amdgcn_mfma_f32_16x16x32_bf16(af[mi], bfr[ni], acc[mi][ni], 0, 0, 0);
    }
    __syncthreads();
  }

#pragma unroll
  for (int ni = 0; ni < 4; ++ni) {
    int colg = n0 + wn * 64 + ni * 16 + l15;
    float bb = b2[e * DMODEL + colg];
#pragma unroll
    for (int mi = 0; mi < 4; ++mi) {
      f32x4 v = acc[mi][ni];
#pragma unroll
      for (int qq = 0; qq < 4; ++qq) {
        int ml2 = m0 + wm * 64 + mi * 16 + u4 * 4 + qq;
        if (ml2 < cnt) {
          int g = off + ml2;
          float* op = out + (size_t)tokg[g] * DMODEL + colg;
          float pv = v[qq];
          if (chunk == 0 && nchunks > 1) {
            *op = pv;
          } else if (chunk < nchunks - 1) {
            *op += pv;
          } else {
            float prev = (nchunks > 1) ? *op : 0.f;
            *op = (prev + pv + bb) * gateg[g];
          }
        }
      }
    }
  }
}

extern "C" void kernel_launch(void* const* d_in, const int* in_sizes, int n_in,
                              void* d_out, int out_size, void* d_ws, size_t ws_size,
                              hipStream_t stream) {
  (void)in_sizes; (void)n_in; (void)out_size;
  const float* x  = (const float*)d_in[0];
  const float* Wg = (const float*)d_in[1];
  const float* bg = (const float*)d_in[2];
  const float* W1 = (const float*)d_in[3];
  const float* b1 = (const float*)d_in[4];
  const float* W2 = (const float*)d_in[5];
  const float* b2 = (const float*)d_in[6];
  float* out = (float*)d_out;
  char* ws = (char*)d_ws;

  size_t cur = 0;
  auto take = [&](size_t bytes) -> size_t {
    cur = (cur + 255) & ~(size_t)255;
    size_t r = cur; cur += bytes; return r;
  };
  size_t o_counts = take(64);
  size_t o_perm  = take((size_t)NEXP * T_TOK * 4);
  size_t o_route = take((size_t)T_TOK * 4);
  size_t o_gate  = take((size_t)T_TOK * 4);
  size_t o_tokg  = take((size_t)(T_TOK + 512) * 4);
  size_t o_gateg = take((size_t)(T_TOK + 512) * 4);
  size_t o_w1t   = take((size_t)NEXP * (DMODEL / 64) * (DFF / 64) * 4096 * 2);
  size_t o_w2t   = take((size_t)NEXP * (DFF / 64) * (DMODEL / 64) * 4096 * 2);
  size_t o_xg    = take((size_t)(MBLK_MAX + 1) * (DMODEL / 64) * 8192 * 2);  // +1 guard blob
  cur = (cur + 255) & ~(size_t)255;
  size_t o_h = cur;

  int FFC = 256;
  const int cands[4] = {3072, 1536, 768, 256};
  for (int i = 0; i < 4; ++i) {
    size_t hbytes = (size_t)MBLK_MAX * (cands[i] >> 6) * 16384;  // tiled h
    if (o_h + hbytes <= ws_size) { FFC = cands[i]; break; }
  }

  int*   counts = (int*)(ws + o_counts);
  int*   perm   = (int*)(ws + o_perm);
  int*   routeb = (int*)(ws + o_route);
  float* gate   = (float*)(ws + o_gate);
  int*   tokg   = (int*)(ws + o_tokg);
  float* gateg  = (float*)(ws + o_gateg);
  short* w1t    = (short*)(ws + o_w1t);
  short* w2t    = (short*)(ws + o_w2t);
  short* xg     = (short*)(ws + o_xg);
  short* hbuf   = (short*)(ws + o_h);

  hipMemsetAsync(counts, 0, 64, stream);
  route_kernel<<<T_TOK / 4, 256, 0, stream>>>(x, Wg, bg, routeb, gate);
  bucket_kernel<<<T_TOK / 256, 256, 0, stream>>>(routeb, counts, perm);
  transpose_tiled_kernel<<<dim3(DMODEL / 64, DFF / 64, NEXP), 256, 0, stream>>>(W1, w1t, DMODEL, DFF);
  transpose_tiled_kernel<<<dim3(DFF / 64, DMODEL / 64, NEXP), 256, 0, stream>>>(W2, w2t, DFF, DMODEL);
  gather_kernel<<<dim3(T_TOK / 8, NEXP), 256, 0, stream>>>(x, counts, perm, gate, xg, tokg, gateg);

  int NC = DFF / FFC;
  int MB256 = T_TOK / 256 + (NEXP - 1);                // 67 max 256-tiles
  int MBG = T_TOK / 128 + (NEXP - 1);                  // 131 max 128-tiles
  for (int c = 0; c < NC; ++c) {
    int NPAN1 = FFC / 128;
    int SGC1 = (MB256 + 7) / 8;                        // 9 supergroups of 8 (256-row)
    gemm1_kernel<<<SGC1 * 8 * NPAN1, 512, 0, stream>>>(xg, w1t, b1, counts, hbuf, FFC, c, NPAN1);
    int NPAN2 = DMODEL / 256;                          // 3
    int SGC2 = (MBG + 3) / 4;                          // 33 supergroups of 4
    gemm2_kernel<<<SGC2 * 4 * NPAN2, 512, 0, stream>>>(hbuf, w2t, b2, counts, tokg, gateg, out, FFC, c, NC, NPAN2);
  }
}